// Round 13
// baseline (607.951 us; speedup 1.0000x reference)
//
#include <hip/hip_runtime.h>
#include <hip/hip_bf16.h>

#define WIN 16
#define SLOTS 10
#define SS 4096
#define NTOK 8192
#define NKV 8212
#define NPOS 4106
#define NATTB 2048
#define NKVB 2053
#define CVT_N 3932160

typedef unsigned short u16;
typedef unsigned int u32;
typedef __attribute__((ext_vector_type(8))) short short8;
typedef __attribute__((ext_vector_type(4))) float f32x4;

__device__ __forceinline__ u16 f2bf(float f){
  union { float f; u32 u; } a; a.f = f;
  u32 r = (a.u + 0x7fff + ((a.u >> 16) & 1)) >> 16;
  return (u16)r;
}
__device__ __forceinline__ float bf2f(u16 v){
  union { u32 u; float f; } a; a.u = ((u32)v) << 16;
  return a.f;
}
__device__ __forceinline__ float wred(float v){
  #pragma unroll
  for (int off=32; off; off>>=1) v += __shfl_xor(v, off, 64);
  return v;
}

#define GLOAD(gp, lp) __builtin_amdgcn_global_load_lds( \
    (const __attribute__((address_space(1))) void*)(gp), \
    (__attribute__((address_space(3))) void*)(lp), 16, 0, 0)

#define FENCE_BARRIER() do { \
    __builtin_amdgcn_sched_barrier(0); \
    __builtin_amdgcn_s_barrier(); \
    __builtin_amdgcn_sched_barrier(0); \
  } while(0)

// ---------------------------------------------------------------- fused weight cvt f32->bf16 (grid-stride)
__global__ __launch_bounds__(256) void cvt_all(
    const float4* __restrict__ s0, const float4* __restrict__ s1,
    const float4* __restrict__ s2, const float4* __restrict__ s3,
    const float4* __restrict__ s4, const float4* __restrict__ s5,
    const float4* __restrict__ s6, const float4* __restrict__ s7,
    ushort4* __restrict__ d0, ushort4* __restrict__ d1,
    ushort4* __restrict__ d2, ushort4* __restrict__ d3,
    ushort4* __restrict__ d4, ushort4* __restrict__ d5,
    ushort4* __restrict__ d6, ushort4* __restrict__ d7)
{
  for (int i = blockIdx.x * 256 + threadIdx.x; i < CVT_N; i += 2048*256){
    const float4* s; ushort4* d; int base;
    if      (i <  262144){ s=s0; d=d0; base=0; }
    else if (i <  524288){ s=s1; d=d1; base=262144; }
    else if (i <  786432){ s=s2; d=d2; base=524288; }
    else if (i < 1048576){ s=s3; d=d3; base=786432; }
    else if (i < 1310720){ s=s4; d=d4; base=1048576; }
    else if (i < 1835008){ s=s5; d=d5; base=1310720; }
    else if (i < 2883584){ s=s6; d=d6; base=1835008; }
    else                 { s=s7; d=d7; base=2883584; }
    float4 v = s[i - base];
    ushort4 o; o.x=f2bf(v.x); o.y=f2bf(v.y); o.z=f2bf(v.z); o.w=f2bf(v.w);
    d[i - base] = o;
  }
}

// ---------------------------------------------------------------- wave-per-token attn+LN1 / wave-per-row kv-norm
__global__ __launch_bounds__(256) void attn_kv(
    const float* __restrict__ x, const float* __restrict__ P,
    const float* __restrict__ g1, const float* __restrict__ be1,
    u16* __restrict__ x1b, u16* __restrict__ kn)
{
  const int blk = blockIdx.x;
  const int t = threadIdx.x, lane = t & 63, wid = t >> 6;
  if (blk >= NATTB){
    const int r = (blk - NATTB)*4 + wid;
    if (r >= NKV) return;
    const int b = r / NPOS;
    const int pos = r - b*NPOS;
    const float4* src = (const float4*)((pos < SS) ? (x + (((size_t)b*SS + pos) << 10))
                                                   : (P + ((size_t)(pos - SS) << 10)));
    float4 v[4];
    float ss = 0.f;
    #pragma unroll
    for (int e=0;e<4;e++){
      v[e] = src[(lane<<2)+e];
      ss += v[e].x*v[e].x + v[e].y*v[e].y + v[e].z*v[e].z + v[e].w*v[e].w;
    }
    ss = wred(ss);
    float inv = 1.f / fmaxf(sqrtf(ss), 1e-12f);
    ushort4* dst = (ushort4*)kn + ((size_t)r << 8);
    #pragma unroll
    for (int e=0;e<4;e++){
      ushort4 o; o.x=f2bf(v[e].x*inv); o.y=f2bf(v[e].y*inv); o.z=f2bf(v[e].z*inv); o.w=f2bf(v[e].w*inv);
      dst[(lane<<2)+e] = o;
    }
    return;
  }
  const int n = blk*4 + wid;
  const int b = n >> 12, s = n & 4095;
  const float* xb = x + ((size_t)b << 22);
  const float4* qp = (const float4*)(xb + ((size_t)s << 10));
  float4 q[4];
  #pragma unroll
  for (int e=0;e<4;e++) q[e] = qp[(lane<<2)+e];

  const int j0 = (s >= WIN) ? 0 : (WIN - s);
  float m = -3.0e38f, l = 0.f;
  float4 o[4];
  #pragma unroll
  for (int e=0;e<4;e++) o[e] = make_float4(0.f,0.f,0.f,0.f);

  for (int j = j0; j < 17; ++j){
    const float4* kp_ = (const float4*)(xb + ((size_t)(s - WIN + j) << 10));
    float4 kk[4];
    float dp = 0.f;
    #pragma unroll
    for (int e=0;e<4;e++){
      kk[e] = kp_[(lane<<2)+e];
      dp += q[e].x*kk[e].x + q[e].y*kk[e].y + q[e].z*kk[e].z + q[e].w*kk[e].w;
    }
    dp = wred(dp) * 0.03125f;
    float mn = fmaxf(m, dp);
    float sc = __expf(m - mn);
    float e_ = __expf(dp - mn);
    l = l*sc + e_;
    #pragma unroll
    for (int e=0;e<4;e++){
      o[e].x = o[e].x*sc + e_*kk[e].x;
      o[e].y = o[e].y*sc + e_*kk[e].y;
      o[e].z = o[e].z*sc + e_*kk[e].z;
      o[e].w = o[e].w*sc + e_*kk[e].w;
    }
    m = mn;
  }
  const float il = 1.f / l;
  float s1 = 0.f, s2 = 0.f;
  float4 y[4];
  #pragma unroll
  for (int e=0;e<4;e++){
    y[e].x = q[e].x + o[e].x*il;
    y[e].y = q[e].y + o[e].y*il;
    y[e].z = q[e].z + o[e].z*il;
    y[e].w = q[e].w + o[e].w*il;
    s1 += y[e].x + y[e].y + y[e].z + y[e].w;
    s2 += y[e].x*y[e].x + y[e].y*y[e].y + y[e].z*y[e].z + y[e].w*y[e].w;
  }
  s1 = wred(s1); s2 = wred(s2);
  float mean = s1 * (1.f/1024.f);
  float var  = s2 * (1.f/1024.f) - mean*mean;
  float rstd = 1.f/sqrtf(var + 1e-5f);
  ushort4* dst = (ushort4*)x1b + ((size_t)n << 8);
  #pragma unroll
  for (int e=0;e<4;e++){
    float4 gv = ((const float4*)g1)[(lane<<2)+e];
    float4 bv = ((const float4*)be1)[(lane<<2)+e];
    ushort4 ob;
    ob.x = f2bf((y[e].x-mean)*rstd*gv.x + bv.x);
    ob.y = f2bf((y[e].y-mean)*rstd*gv.y + bv.y);
    ob.z = f2bf((y[e].z-mean)*rstd*gv.z + bv.z);
    ob.w = f2bf((y[e].w-mean)*rstd*gv.w + bv.w);
    dst[(lane<<2)+e] = ob;
  }
}

// ---------------------------------------------------------------- generic NT GEMM 128x128, 4-slot K32 pipeline
template<int EPI, int SPLITA>
__global__ __launch_bounds__(256) void gemm_nt(
    const u16* __restrict__ A, const u16* __restrict__ A2,
    const u16* __restrict__ Bmat, const float* __restrict__ bias,
    const u16* __restrict__ auxb,
    float* __restrict__ Cf, u16* __restrict__ Cb,
    int N, int O, int ldA, int ldB, int klen)
{
  __shared__ __align__(16) u16 lA[4][128*32];
  __shared__ __align__(16) u16 lB[4][128*32];
  const int t = threadIdx.x;
  const int lane = t & 63;
  const int bm0 = blockIdx.x * 128;
  const int bn0 = blockIdx.y * 128;
  const int wid = t >> 6;
  const int wr = wid >> 1, wc = wid & 1;
  const int nkh = klen >> 5;            // K-halves of 32

  f32x4 acc[4][4];
  #pragma unroll
  for (int i=0;i<4;i++)
    #pragma unroll
    for (int j=0;j<4;j++)
      acc[i][j] = (f32x4){0.f,0.f,0.f,0.f};

  const int srow = t >> 2;              // 0..63 (rows srow, srow+64)
  const int sch  = t & 3;
  const int csw  = ((sch ^ ((srow >> 1) & 3)) << 3);

  int gr0 = bm0 + srow;      gr0 = gr0 < N ? gr0 : N-1;
  int gr1 = bm0 + srow + 64; gr1 = gr1 < N ? gr1 : N-1;
  int gb0 = bn0 + srow;      gb0 = gb0 < O ? gb0 : O-1;
  int gb1 = bn0 + srow + 64; gb1 = gb1 < O ? gb1 : O-1;
  const u16* bA0 = A + (size_t)gr0*(size_t)ldA + csw;
  const u16* bA1 = A + (size_t)gr1*(size_t)ldA + csw;
  const u16* bA20 = SPLITA ? (A2 + ((size_t)gr0 << 10) + csw) : nullptr;
  const u16* bA21 = SPLITA ? (A2 + ((size_t)gr1 << 10) + csw) : nullptr;
  const u16* bB0 = Bmat + (size_t)gb0*(size_t)ldB + csw;
  const u16* bB1 = Bmat + (size_t)gb1*(size_t)ldB + csw;
  const int dLo = t << 3;
  const int dHi = (t << 3) + 2048;

  auto stage = [&](int j){
    const int kb = j << 5;
    const int s = j & 3;
    const u16* a0 = SPLITA ? ((kb < 1024) ? bA0 + kb : bA20 + (kb - 1024)) : bA0 + kb;
    const u16* a1 = SPLITA ? ((kb < 1024) ? bA1 + kb : bA21 + (kb - 1024)) : bA1 + kb;
    GLOAD(a0, &lA[s][dLo]);
    GLOAD(a1, &lA[s][dHi]);
    GLOAD(bB0 + kb, &lB[s][dLo]);
    GLOAD(bB1 + kb, &lB[s][dHi]);
  };

  stage(0);
  if (nkh > 1) stage(1);
  if (nkh > 2) stage(2);

  const int l15 = lane & 15;
  const int cq  = lane >> 4;
  const int soff = ((cq ^ ((l15 >> 1) & 3)) << 3);

  for (int j = 0; j < nkh; ++j){
    const int s = j & 3;
    const int cnt = 4*((j+1 < nkh) + (j+2 < nkh));
    if (cnt == 8)      { asm volatile("s_waitcnt vmcnt(8)" ::: "memory"); }
    else if (cnt == 4) { asm volatile("s_waitcnt vmcnt(4)" ::: "memory"); }
    else               { asm volatile("s_waitcnt vmcnt(0)" ::: "memory"); }
    FENCE_BARRIER();
    short8 af[4], bfv[4];
    #pragma unroll
    for (int mi=0;mi<4;mi++)
      af[mi] = *(const short8*)(&lA[s][((wr*64 + mi*16 + l15) * 32) + soff]);
    #pragma unroll
    for (int ni=0;ni<4;ni++)
      bfv[ni] = *(const short8*)(&lB[s][((wc*64 + ni*16 + l15) * 32) + soff]);
    if (j + 3 < nkh) stage(j + 3);
    __builtin_amdgcn_sched_barrier(0);
    __builtin_amdgcn_s_setprio(1);
    #pragma unroll
    for (int mi=0;mi<4;mi++)
      #pragma unroll
      for (int ni=0;ni<4;ni++)
        acc[mi][ni] = __builtin_amdgcn_mfma_f32_16x16x32_bf16(af[mi], bfv[ni], acc[mi][ni], 0, 0, 0);
    __builtin_amdgcn_s_setprio(0);
    __builtin_amdgcn_sched_barrier(0);
  }

  const int rbase = (lane >> 4) * 4;
  const int cidx = lane & 15;
  #pragma unroll
  for (int mi=0;mi<4;mi++){
    #pragma unroll
    for (int r=0;r<4;r++){
      const int n = bm0 + wr*64 + mi*16 + rbase + r;
      if (n >= N) continue;
      #pragma unroll
      for (int ni=0;ni<4;ni++){
        const int o = bn0 + wc*64 + ni*16 + cidx;
        float v = acc[mi][ni][r] + bias[o];
        if (EPI == 6){
          int b = n / NPOS;
          int pos = n - b*NPOS;
          if (pos < SS){
            Cb[(((size_t)(b*SS + pos)) << 10) + o] = f2bf(v);
          }
        } else {
          size_t idx = (size_t)n*(size_t)O + o;
          if (EPI == 0){ Cf[idx] = v; }
          else if (EPI == 1){ float sv = v/(1.f+__expf(-v)); Cb[idx] = f2bf(sv); }
          else if (EPI == 2){ Cb[idx] = f2bf(v); }
          else if (EPI == 4){ Cb[idx] = f2bf(v - bf2f(auxb[idx])); }
          else if (EPI == 5){ Cb[idx] = f2bf(1.f/(1.f+__expf(-v))); }
        }
      }
    }
  }
}

// ---------------------------------------------------------------- big NT GEMM 256x256, 2-slot BK=64
// Per K-tile(64): {vmcnt(8|0); FENCE; [kk=0: 12 ds_read + 32 MFMA][kk=1: same];
//  FENCE; stage(j+2)}  -> 2 barriers per K=64 (half the 4-slot rate).
// Swizzle: lds (r,c) holds global (r, c^(r&7)); read c=(kk*4+cq)^(l15&7).
template<int EPI>
__global__ __launch_bounds__(512, 2) void gemm_256(
    const u16* __restrict__ A, const u16* __restrict__ Bmat,
    const float* __restrict__ bias,
    float* __restrict__ Cf, u16* __restrict__ Cb,
    int N, int O, int ldA, int ldB, int klen)
{
  __shared__ __align__(16) u16 lA[2][256*64];
  __shared__ __align__(16) u16 lB[2][256*64];
  const int t = threadIdx.x;           // 0..511
  const int lane = t & 63;
  const int wid = t >> 6;              // 0..7
  const int wr = wid >> 2, wc = wid & 3;
  const int bm0 = blockIdx.x * 256;
  const int bn0 = blockIdx.y * 256;
  const int nkt = klen >> 6;           // K-tiles of 64

  f32x4 acc[8][4];
  #pragma unroll
  for (int i=0;i<8;i++)
    #pragma unroll
    for (int j=0;j<4;j++)
      acc[i][j] = (f32x4){0.f,0.f,0.f,0.f};

  // staging: rows (t>>3)+64*i (i=0..3), chunk t&7 (8 elems); source pre-swizzled
  const int srow = t >> 3;             // 0..63
  const int sch  = t & 7;
  const int csw  = ((sch ^ (srow & 7)) << 3);
  const u16* baseA[4]; const u16* baseB[4];
  #pragma unroll
  for (int i=0;i<4;i++){
    int gr = bm0 + srow + i*64; gr = gr < N ? gr : N-1;
    baseA[i] = A + (size_t)gr*(size_t)ldA + csw;
    int gb = bn0 + srow + i*64; gb = gb < O ? gb : O-1;
    baseB[i] = Bmat + (size_t)gb*(size_t)ldB + csw;
  }
  const int dbase = srow*64 + (sch << 3);

  auto stage = [&](int j){
    const int kb = j << 6;
    const int s = j & 1;
    #pragma unroll
    for (int i=0;i<4;i++){
      GLOAD(baseA[i] + kb, &lA[s][dbase + i*4096]);
      GLOAD(baseB[i] + kb, &lB[s][dbase + i*4096]);
    }
  };

  stage(0);
  if (nkt > 1) stage(1);

  const int l15 = lane & 15;
  const int cq  = lane >> 4;
  const int rx  = l15 & 7;

  for (int j = 0; j < nkt; ++j){
    const int s = j & 1;
    if (j + 1 < nkt) { asm volatile("s_waitcnt vmcnt(8)" ::: "memory"); }
    else             { asm volatile("s_waitcnt vmcnt(0)" ::: "memory"); }
    FENCE_BARRIER();                    // tile j landed for all waves
    #pragma unroll
    for (int kk=0; kk<2; kk++){
      const int soff = (((kk*4 + cq) ^ rx) << 3);
      short8 af[8], bfv[4];
      #pragma unroll
      for (int ni=0;ni<4;ni++)
        bfv[ni] = *(const short8*)(&lB[s][((wc*64 + ni*16 + l15) << 6) + soff]);
      #pragma unroll
      for (int mi=0;mi<8;mi++)
        af[mi] = *(const short8*)(&lA[s][((wr*128 + mi*16 + l15) << 6) + soff]);
      __builtin_amdgcn_sched_barrier(0);
      __builtin_amdgcn_s_setprio(1);
      #pragma unroll
      for (int mi=0;mi<8;mi++)
        #pragma unroll
        for (int ni=0;ni<4;ni++)
          acc[mi][ni] = __builtin_amdgcn_mfma_f32_16x16x32_bf16(af[mi], bfv[ni], acc[mi][ni], 0, 0, 0);
      __builtin_amdgcn_s_setprio(0);
      __builtin_amdgcn_sched_barrier(0);
    }
    FENCE_BARRIER();                    // all waves done reading slot s
    if (j + 2 < nkt) stage(j + 2);      // overwrite slot s with tile j+2
  }

  const int rbase = (lane >> 4) * 4;
  const int cidx = lane & 15;
  #pragma unroll
  for (int mi=0;mi<8;mi++){
    #pragma unroll
    for (int r=0;r<4;r++){
      const int n = bm0 + wr*128 + mi*16 + rbase + r;
      if (n >= N) continue;
      #pragma unroll
      for (int ni=0;ni<4;ni++){
        const int o = bn0 + wc*64 + ni*16 + cidx;
        float v = acc[mi][ni][r] + bias[o];
        size_t idx = (size_t)n*(size_t)O + o;
        if (EPI == 0){ Cf[idx] = v; }
        else if (EPI == 1){ float sv = v/(1.f+__expf(-v)); Cb[idx] = f2bf(sv); }
        else if (EPI == 2){ Cb[idx] = f2bf(v); }
      }
    }
  }
}

// ---------------------------------------------------------------- TN GEMM for grad_W (reg-prefetch, swizzled LDS)
#define NSPLIT 6
__global__ __launch_bounds__(256) void gemm_tn(
    const u16* __restrict__ A, const u16* __restrict__ B,
    float* __restrict__ part0, float* __restrict__ part1)
{
  __shared__ __align__(16) u16 lA[128*64];
  __shared__ __align__(16) u16 lB[128*64];
  const int t = threadIdx.x, lane = t & 63;
  const int i0 = blockIdx.x * 128, j0 = blockIdx.y * 128, z = blockIdx.z;
  const int wid = t >> 6, wr = wid >> 1, wc = wid & 1;
  const int TILES = (NKV + 63) >> 6;
  const int PER = (TILES + NSPLIT - 1) / NSPLIT;
  const int kt0 = z * PER;
  const int ktend = (kt0 + PER < TILES) ? (kt0 + PER) : TILES;

  f32x4 acc[4][4];
  #pragma unroll
  for (int i=0;i<4;i++)
    #pragma unroll
    for (int j=0;j<4;j++)
      acc[i][j] = (f32x4){0.f,0.f,0.f,0.f};

  const int p = t & 31;
  const int g = t >> 5;

  auto loadr = [&](int kt, short8 R[8]){
    const int n0 = kt << 6;
    const int na = n0 + 2*p, nb = na + 1;
    short8 z8 = (short8){0,0,0,0,0,0,0,0};
    R[0]=z8;R[1]=z8;R[2]=z8;R[3]=z8;R[4]=z8;R[5]=z8;R[6]=z8;R[7]=z8;
    if (na < NKV){
      const u16* ra = A + (size_t)na*1024 + i0 + g*16;
      R[0] = *(const short8*)ra; R[1] = *(const short8*)(ra+8);
      const u16* rb = B + (size_t)na*1024 + j0 + g*16;
      R[4] = *(const short8*)rb; R[5] = *(const short8*)(rb+8);
    }
    if (nb < NKV){
      const u16* ra = A + (size_t)nb*1024 + i0 + g*16;
      R[2] = *(const short8*)ra; R[3] = *(const short8*)(ra+8);
      const u16* rb = B + (size_t)nb*1024 + j0 + g*16;
      R[6] = *(const short8*)rb; R[7] = *(const short8*)(rb+8);
    }
  };

  short8 cr[8], nr[8];
  loadr(kt0, cr);

  const int pc = p >> 2, pl = p & 3;

  for (int kt = kt0; kt < ktend; ++kt){
    if (kt + 1 < ktend) loadr(kt + 1, nr);
    asm volatile("" ::: "memory");
    FENCE_BARRIER();
    u32* wA = (u32*)lA; u32* wB = (u32*)lB;
    #pragma unroll
    for (int e=0;e<8;e++){
      const int s = (pc ^ e) * 4 + pl;
      wA[(g*16 + e)*32 + s]     = ((u32)(u16)cr[0][e]) | (((u32)(u16)cr[2][e]) << 16);
      wB[(g*16 + e)*32 + s]     = ((u32)(u16)cr[4][e]) | (((u32)(u16)cr[6][e]) << 16);
    }
    #pragma unroll
    for (int e=0;e<8;e++){
      const int s = (pc ^ e) * 4 + pl;
      wA[(g*16 + 8 + e)*32 + s] = ((u32)(u16)cr[1][e]) | (((u32)(u16)cr[3][e]) << 16);
      wB[(g*16 + 8 + e)*32 + s] = ((u32)(u16)cr[5][e]) | (((u32)(u16)cr[7][e]) << 16);
    }
    asm volatile("s_waitcnt lgkmcnt(0)" ::: "memory");
    FENCE_BARRIER();
    const int l15 = lane & 15;
    const int rx = l15 & 7;
    const int cq = lane >> 4;
    #pragma unroll
    for (int kk=0;kk<2;kk++){
      const int soff = (((kk*4 + cq) ^ rx) << 3);
      short8 af[4], bfv[4];
      #pragma unroll
      for (int mi=0;mi<4;mi++)
        af[mi] = *(const short8*)(lA + ((wr*64 + mi*16 + l15) << 6) + soff);
      #pragma unroll
      for (int ni=0;ni<4;ni++)
        bfv[ni] = *(const short8*)(lB + ((wc*64 + ni*16 + l15) << 6) + soff);
      #pragma unroll
      for (int mi=0;mi<4;mi++)
        #pragma unroll
        for (int ni=0;ni<4;ni++)
          acc[mi][ni] = __builtin_amdgcn_mfma_f32_16x16x32_bf16(af[mi], bfv[ni], acc[mi][ni], 0, 0, 0);
    }
    #pragma unroll
    for (int e=0;e<8;e++) cr[e] = nr[e];
  }

  float* dst = (z < 4) ? (part0 + ((size_t)z << 20)) : (part1 + ((size_t)(z-4) << 20));
  const int rbase = (lane >> 4) * 4;
  const int cidx = lane & 15;
  #pragma unroll
  for (int mi=0;mi<4;mi++)
    #pragma unroll
    for (int r=0;r<4;r++){
      const int i = i0 + wr*64 + mi*16 + rbase + r;
      #pragma unroll
      for (int ni=0;ni<4;ni++){
        const int j = j0 + wc*64 + ni*16 + cidx;
        dst[((size_t)i << 10) + j] = acc[mi][ni][r];
      }
    }
}

// ---------------------------------------------------------------- W_new
__global__ __launch_bounds__(256) void wnew_k(const float* __restrict__ part0,
                                              const float* __restrict__ part1,
                                              const float* __restrict__ memW,
                                              const float* __restrict__ fg,
                                              const float* __restrict__ lr,
                                              u16* __restrict__ out)
{
  int i = blockIdx.x*256 + threadIdx.x;
  float s = part0[i] + part0[i + (1<<20)] + part0[i + (2<<20)] + part0[i + (3<<20)]
          + part1[i] + part1[i + (1<<20)];
  const float scale = 2.f / ((float)NKV * 1024.f);
  float v = (1.f - fg[0])*memW[i] + lr[0]*scale*s;
  out[i] = f2bf(v);
}

// ---------------------------------------------------------------- x2 = LN(x1 + gate*x1 + (1-gate)*mo)
__global__ __launch_bounds__(256) void ln_gate(
    const u16* __restrict__ x1b, const u16* __restrict__ gateb,
    const u16* __restrict__ mob, const float* __restrict__ g2,
    const float* __restrict__ be2, u16* __restrict__ x2b)
{
  const int n = blockIdx.x;
  const int t = threadIdx.x, lane = t & 63, w = t >> 6;
  const size_t rb = (size_t)n << 8;
  ushort4 xa = ((const ushort4*)x1b)[rb+t];
  ushort4 ga = ((const ushort4*)gateb)[rb+t];
  ushort4 ma = ((const ushort4*)mob)[rb+t];
  float a0=bf2f(xa.x),a1=bf2f(xa.y),a2=bf2f(xa.z),a3=bf2f(xa.w);
  float g0=bf2f(ga.x),g1v=bf2f(ga.y),g2v=bf2f(ga.z),g3v=bf2f(ga.w);
  float m0=bf2f(ma.x),m1=bf2f(ma.y),m2=bf2f(ma.z),m3=bf2f(ma.w);
  float y0 = a0 + g0*a0 + (1.f-g0)*m0;
  float y1 = a1 + g1v*a1 + (1.f-g1v)*m1;
  float y2 = a2 + g2v*a2 + (1.f-g2v)*m2;
  float y3 = a3 + g3v*a3 + (1.f-g3v)*m3;
  float s1 = y0+y1+y2+y3;
  float s2 = y0*y0+y1*y1+y2*y2+y3*y3;
  #pragma unroll
  for (int off=32; off; off>>=1){ s1 += __shfl_xor(s1, off, 64); s2 += __shfl_xor(s2, off, 64); }
  __shared__ float rsh[8];
  if (lane == 0){ rsh[w] = s1; rsh[4+w] = s2; }
  __syncthreads();
  float S1 = rsh[0]+rsh[1]+rsh[2]+rsh[3];
  float S2 = rsh[4]+rsh[5]+rsh[6]+rsh[7];
  float mean = S1 * (1.f/1024.f);
  float var  = S2 * (1.f/1024.f) - mean*mean;
  float rstd = 1.f/sqrtf(var + 1e-5f);
  float4 gv = ((const float4*)g2)[t];
  float4 bv = ((const float4*)be2)[t];
  ushort4 ob;
  ob.x = f2bf((y0-mean)*rstd*gv.x + bv.x);
  ob.y = f2bf((y1-mean)*rstd*gv.y + bv.y);
  ob.z = f2bf((y2-mean)*rstd*gv.z + bv.z);
  ob.w = f2bf((y3-mean)*rstd*gv.w + bv.w);
  ((ushort4*)x2b)[rb + t] = ob;
}

// ---------------------------------------------------------------- out = LN(x2 + ff2) (ff2 in d_out, in-place)
__global__ __launch_bounds__(256) void ln_final(
    const u16* __restrict__ x2b, const float* __restrict__ g3,
    const float* __restrict__ be3, float* __restrict__ out)
{
  const int n = blockIdx.x;
  const int t = threadIdx.x, lane = t & 63, w = t >> 6;
  const size_t rb = (size_t)n << 8;
  ushort4 xa = ((const ushort4*)x2b)[rb+t];
  float4 f = ((const float4*)out)[rb+t];
  float y0 = bf2f(xa.x)+f.x, y1 = bf2f(xa.y)+f.y, y2 = bf2f(xa.z)+f.z, y3 = bf2f(xa.w)+f.w;
  float s1 = y0+y1+y2+y3;
  float s2 = y0*y0+y1*y1+y2*y2+y3*y3;
  #pragma unroll
  for (int off=32; off; off>>=1){ s1 += __shfl_xor(s1, off, 64); s2 += __shfl_xor(s2, off, 64); }
  __shared__ float rsh[8];
  if (lane == 0){ rsh[w] = s1; rsh[4+w] = s2; }
  __syncthreads();
  float S1 = rsh[0]+rsh[1]+rsh[2]+rsh[3];
  float S2 = rsh[4]+rsh[5]+rsh[6]+rsh[7];
  float mean = S1 * (1.f/1024.f);
  float var  = S2 * (1.f/1024.f) - mean*mean;
  float rstd = 1.f/sqrtf(var + 1e-5f);
  float4 gv = ((const float4*)g3)[t];
  float4 bv = ((const float4*)be3)[t];
  float4 o;
  o.x = (y0-mean)*rstd*gv.x + bv.x;
  o.y = (y1-mean)*rstd*gv.y + bv.y;
  o.z = (y2-mean)*rstd*gv.z + bv.z;
  o.w = (y3-mean)*rstd*gv.w + bv.w;
  ((float4*)out)[rb + t] = o;
}

// ================================================================ host
extern "C" void kernel_launch(void* const* d_in, const int* in_sizes, int n_in,
                              void* d_out, int out_size, void* d_ws, size_t ws_size,
                              hipStream_t stream)
{
  const float* x    = (const float*)d_in[0];
  const float* memW = (const float*)d_in[1];
  const float* memb = (const float*)d_in[2];
  const float* P    = (const float*)d_in[3];
  const float* Wi   = (const float*)d_in[4];
  const float* bi   = (const float*)d_in[5];
  const float* Wl1  = (const float*)d_in[6];
  const float* bl1  = (const float*)d_in[7];
  const float* Wl2  = (const float*)d_in[8];
  const float* bl2  = (const float*)d_in[9];
  const float* Wo   = (const float*)d_in[10];
  const float* bo   = (const float*)d_in[11];
  const float* fg   = (const float*)d_in[12];
  const float* lr   = (const float*)d_in[13];
  const float* Wg   = (const float*)d_in[14];
  const float* bg   = (const float*)d_in[15];
  const float* W1   = (const float*)d_in[16];
  const float* b1   = (const float*)d_in[17];
  const float* W2   = (const float*)d_in[18];
  const float* b2   = (const float*)d_in[19];
  const float* g1   = (const float*)d_in[20];
  const float* be1  = (const float*)d_in[21];
  const float* g2   = (const float*)d_in[22];
  const float* be2  = (const float*)d_in[23];
  const float* g3   = (const float*)d_in[24];
  const float* be3  = (const float*)d_in[25];
  float* out = (float*)d_out;

  const size_t SZ_TOK = (size_t)NTOK*1024*2;
  const size_t SZ_KV  = (size_t)NKV*1024*2;
  char* base = (char*)d_ws;
  size_t off = 0;
  auto alloc = [&](size_t bytes) -> char* {
    char* p = base + off;
    off += (bytes + 255) & ~(size_t)255;
    return p;
  };
  u16* x1b   = (u16*)alloc(SZ_TOK);
  u16* knb   = (u16*)alloc(SZ_KV);
  u16* h1b   = (u16*)alloc(SZ_KV);
  u16* hddb  = (u16*)alloc(SZ_KV);
  u16* kpb   = (u16*)alloc(SZ_KV);
  u16* wnewb = (u16*)alloc((size_t)1024*1024*2);
  u16* WiB   = (u16*)alloc((size_t)1024*1024*2);   // } contiguous 8 MiB, dead after use:
  u16* Wl1B  = (u16*)alloc((size_t)1024*1024*2);   // } reused as grad partial slices 4-5
  u16* Wl2B  = (u16*)alloc((size_t)1024*1024*2);
  u16* memWB = (u16*)alloc((size_t)1024*1024*2);
  u16* WoB   = (u16*)alloc((size_t)1024*1024*2);
  u16* WgB   = (u16*)alloc((size_t)1024*2048*2);
  u16* W1B   = (u16*)alloc((size_t)4096*1024*2);
  u16* W2B   = (u16*)alloc((size_t)1024*4096*2);
  if (ws_size < off) return;   // diagnostic guard

  u16*   diffb   = knb;
  float* part0   = (float*)kpb;
  float* part1   = (float*)WiB;
  u16*   memoutb = knb;
  u16*   mob     = h1b;
  u16*   gateb   = hddb;
  u16*   x2b     = kpb;
  u16*   ff1b    = x1b;

  cvt_all<<<2048, 256, 0, stream>>>(
      (const float4*)Wi, (const float4*)Wl1, (const float4*)Wl2, (const float4*)memW,
      (const float4*)Wo, (const float4*)Wg, (const float4*)W1, (const float4*)W2,
      (ushort4*)WiB, (ushort4*)Wl1B, (ushort4*)Wl2B, (ushort4*)memWB,
      (ushort4*)WoB, (ushort4*)WgB, (ushort4*)W1B, (ushort4*)W2B);

  attn_kv<<<NATTB + NKVB, 256, 0, stream>>>(x, P, g1, be1, x1b, knb);

  dim3 gkv(65, 8, 1);
  gemm_nt<2,0><<<gkv, 256, 0, stream>>>(knb, nullptr, WiB, bi, nullptr, nullptr, kpb, NKV, 1024, 1024, 1024, 1024);
  gemm_nt<1,0><<<gkv, 256, 0, stream>>>(kpb, nullptr, Wl1B, bl1, nullptr, nullptr, h1b, NKV, 1024, 1024, 1024, 1024);
  gemm_nt<1,0><<<gkv, 256, 0, stream>>>(h1b, nullptr, Wl2B, bl2, nullptr, nullptr, hddb, NKV, 1024, 1024, 1024, 1024);
  gemm_nt<4,0><<<gkv, 256, 0, stream>>>(hddb, nullptr, memWB, memb, kpb, nullptr, diffb, NKV, 1024, 1024, 1024, 1024);
  gemm_tn<<<dim3(8, 8, NSPLIT), 256, 0, stream>>>(diffb, hddb, part0, part1);
  wnew_k<<<4096, 256, 0, stream>>>(part0, part1, memW, fg, lr, wnewb);
  gemm_nt<2,0><<<gkv, 256, 0, stream>>>(hddb, nullptr, wnewb, memb, nullptr, nullptr, memoutb, NKV, 1024, 1024, 1024, 1024);
  gemm_nt<6,0><<<gkv, 256, 0, stream>>>(memoutb, nullptr, WoB, bo, nullptr, nullptr, mob, NKV, 1024, 1024, 1024, 1024);
  gemm_nt<5,1><<<dim3(64, 8, 1), 256, 0, stream>>>(x1b, mob, WgB, bg, nullptr, nullptr, gateb, NTOK, 1024, 1024, 2048, 2048);
  ln_gate<<<NTOK, 256, 0, stream>>>(x1b, gateb, mob, g2, be2, x2b);
  // ff1 = silu(x2 @ W1.T + b1) : 256x256 2-slot BK=64 kernel (512 blocks)
  gemm_256<1><<<dim3(32, 16, 1), 512, 0, stream>>>(x2b, W1B, b1, nullptr, ff1b, NTOK, 4096, 1024, 1024, 1024);
  // ff2 = ff1 @ W2.T + b2 -> f32 directly into d_out (128^2, 512 blocks, full chip)
  gemm_nt<0,0><<<dim3(64, 8, 1), 256, 0, stream>>>(ff1b, nullptr, W2B, b2, nullptr, out, nullptr, NTOK, 1024, 4096, 4096, 4096);
  ln_final<<<NTOK, 256, 0, stream>>>(x2b, g3, be3, out);
}

// Round 14
// 599.613 us; speedup vs baseline: 1.0139x; 1.0139x over previous
//
#include <hip/hip_runtime.h>
#include <hip/hip_bf16.h>

#define WIN 16
#define SLOTS 10
#define SS 4096
#define NTOK 8192
#define NKV 8212
#define NPOS 4106
#define NATTB 2048
#define NKVB 2053
#define CVT_N 3932160

typedef unsigned short u16;
typedef unsigned int u32;
typedef __attribute__((ext_vector_type(8))) short short8;
typedef __attribute__((ext_vector_type(4))) float f32x4;

__device__ __forceinline__ u16 f2bf(float f){
  union { float f; u32 u; } a; a.f = f;
  u32 r = (a.u + 0x7fff + ((a.u >> 16) & 1)) >> 16;
  return (u16)r;
}
__device__ __forceinline__ float bf2f(u16 v){
  union { u32 u; float f; } a; a.u = ((u32)v) << 16;
  return a.f;
}
__device__ __forceinline__ float wred(float v){
  #pragma unroll
  for (int off=32; off; off>>=1) v += __shfl_xor(v, off, 64);
  return v;
}

#define GLOAD(gp, lp) __builtin_amdgcn_global_load_lds( \
    (const __attribute__((address_space(1))) void*)(gp), \
    (__attribute__((address_space(3))) void*)(lp), 16, 0, 0)

#define FENCE_BARRIER() do { \
    __builtin_amdgcn_sched_barrier(0); \
    __builtin_amdgcn_s_barrier(); \
    __builtin_amdgcn_sched_barrier(0); \
  } while(0)

// ---------------------------------------------------------------- fused weight cvt f32->bf16 (grid-stride)
__global__ __launch_bounds__(256) void cvt_all(
    const float4* __restrict__ s0, const float4* __restrict__ s1,
    const float4* __restrict__ s2, const float4* __restrict__ s3,
    const float4* __restrict__ s4, const float4* __restrict__ s5,
    const float4* __restrict__ s6, const float4* __restrict__ s7,
    ushort4* __restrict__ d0, ushort4* __restrict__ d1,
    ushort4* __restrict__ d2, ushort4* __restrict__ d3,
    ushort4* __restrict__ d4, ushort4* __restrict__ d5,
    ushort4* __restrict__ d6, ushort4* __restrict__ d7)
{
  for (int i = blockIdx.x * 256 + threadIdx.x; i < CVT_N; i += 2048*256){
    const float4* s; ushort4* d; int base;
    if      (i <  262144){ s=s0; d=d0; base=0; }
    else if (i <  524288){ s=s1; d=d1; base=262144; }
    else if (i <  786432){ s=s2; d=d2; base=524288; }
    else if (i < 1048576){ s=s3; d=d3; base=786432; }
    else if (i < 1310720){ s=s4; d=d4; base=1048576; }
    else if (i < 1835008){ s=s5; d=d5; base=1310720; }
    else if (i < 2883584){ s=s6; d=d6; base=1835008; }
    else                 { s=s7; d=d7; base=2883584; }
    float4 v = s[i - base];
    ushort4 o; o.x=f2bf(v.x); o.y=f2bf(v.y); o.z=f2bf(v.z); o.w=f2bf(v.w);
    d[i - base] = o;
  }
}

// ---------------------------------------------------------------- wave-per-token attn+LN1 / wave-per-row kv-norm
__global__ __launch_bounds__(256) void attn_kv(
    const float* __restrict__ x, const float* __restrict__ P,
    const float* __restrict__ g1, const float* __restrict__ be1,
    u16* __restrict__ x1b, u16* __restrict__ kn)
{
  const int blk = blockIdx.x;
  const int t = threadIdx.x, lane = t & 63, wid = t >> 6;
  if (blk >= NATTB){
    const int r = (blk - NATTB)*4 + wid;
    if (r >= NKV) return;
    const int b = r / NPOS;
    const int pos = r - b*NPOS;
    const float4* src = (const float4*)((pos < SS) ? (x + (((size_t)b*SS + pos) << 10))
                                                   : (P + ((size_t)(pos - SS) << 10)));
    float4 v[4];
    float ss = 0.f;
    #pragma unroll
    for (int e=0;e<4;e++){
      v[e] = src[(lane<<2)+e];
      ss += v[e].x*v[e].x + v[e].y*v[e].y + v[e].z*v[e].z + v[e].w*v[e].w;
    }
    ss = wred(ss);
    float inv = 1.f / fmaxf(sqrtf(ss), 1e-12f);
    ushort4* dst = (ushort4*)kn + ((size_t)r << 8);
    #pragma unroll
    for (int e=0;e<4;e++){
      ushort4 o; o.x=f2bf(v[e].x*inv); o.y=f2bf(v[e].y*inv); o.z=f2bf(v[e].z*inv); o.w=f2bf(v[e].w*inv);
      dst[(lane<<2)+e] = o;
    }
    return;
  }
  const int n = blk*4 + wid;
  const int b = n >> 12, s = n & 4095;
  const float* xb = x + ((size_t)b << 22);
  const float4* qp = (const float4*)(xb + ((size_t)s << 10));
  float4 q[4];
  #pragma unroll
  for (int e=0;e<4;e++) q[e] = qp[(lane<<2)+e];

  const int j0 = (s >= WIN) ? 0 : (WIN - s);
  float m = -3.0e38f, l = 0.f;
  float4 o[4];
  #pragma unroll
  for (int e=0;e<4;e++) o[e] = make_float4(0.f,0.f,0.f,0.f);

  for (int j = j0; j < 17; ++j){
    const float4* kp_ = (const float4*)(xb + ((size_t)(s - WIN + j) << 10));
    float4 kk[4];
    float dp = 0.f;
    #pragma unroll
    for (int e=0;e<4;e++){
      kk[e] = kp_[(lane<<2)+e];
      dp += q[e].x*kk[e].x + q[e].y*kk[e].y + q[e].z*kk[e].z + q[e].w*kk[e].w;
    }
    dp = wred(dp) * 0.03125f;
    float mn = fmaxf(m, dp);
    float sc = __expf(m - mn);
    float e_ = __expf(dp - mn);
    l = l*sc + e_;
    #pragma unroll
    for (int e=0;e<4;e++){
      o[e].x = o[e].x*sc + e_*kk[e].x;
      o[e].y = o[e].y*sc + e_*kk[e].y;
      o[e].z = o[e].z*sc + e_*kk[e].z;
      o[e].w = o[e].w*sc + e_*kk[e].w;
    }
    m = mn;
  }
  const float il = 1.f / l;
  float s1 = 0.f, s2 = 0.f;
  float4 y[4];
  #pragma unroll
  for (int e=0;e<4;e++){
    y[e].x = q[e].x + o[e].x*il;
    y[e].y = q[e].y + o[e].y*il;
    y[e].z = q[e].z + o[e].z*il;
    y[e].w = q[e].w + o[e].w*il;
    s1 += y[e].x + y[e].y + y[e].z + y[e].w;
    s2 += y[e].x*y[e].x + y[e].y*y[e].y + y[e].z*y[e].z + y[e].w*y[e].w;
  }
  s1 = wred(s1); s2 = wred(s2);
  float mean = s1 * (1.f/1024.f);
  float var  = s2 * (1.f/1024.f) - mean*mean;
  float rstd = 1.f/sqrtf(var + 1e-5f);
  ushort4* dst = (ushort4*)x1b + ((size_t)n << 8);
  #pragma unroll
  for (int e=0;e<4;e++){
    float4 gv = ((const float4*)g1)[(lane<<2)+e];
    float4 bv = ((const float4*)be1)[(lane<<2)+e];
    ushort4 ob;
    ob.x = f2bf((y[e].x-mean)*rstd*gv.x + bv.x);
    ob.y = f2bf((y[e].y-mean)*rstd*gv.y + bv.y);
    ob.z = f2bf((y[e].z-mean)*rstd*gv.z + bv.z);
    ob.w = f2bf((y[e].w-mean)*rstd*gv.w + bv.w);
    dst[(lane<<2)+e] = ob;
  }
}

// ---------------------------------------------------------------- generic NT GEMM 128x128, 4-slot K32 pipeline
template<int EPI, int SPLITA>
__global__ __launch_bounds__(256) void gemm_nt(
    const u16* __restrict__ A, const u16* __restrict__ A2,
    const u16* __restrict__ Bmat, const float* __restrict__ bias,
    const u16* __restrict__ auxb,
    float* __restrict__ Cf, u16* __restrict__ Cb,
    int N, int O, int ldA, int ldB, int klen)
{
  __shared__ __align__(16) u16 lA[4][128*32];
  __shared__ __align__(16) u16 lB[4][128*32];
  const int t = threadIdx.x;
  const int lane = t & 63;
  const int bm0 = blockIdx.x * 128;
  const int bn0 = blockIdx.y * 128;
  const int wid = t >> 6;
  const int wr = wid >> 1, wc = wid & 1;
  const int nkh = klen >> 5;            // K-halves of 32

  f32x4 acc[4][4];
  #pragma unroll
  for (int i=0;i<4;i++)
    #pragma unroll
    for (int j=0;j<4;j++)
      acc[i][j] = (f32x4){0.f,0.f,0.f,0.f};

  const int srow = t >> 2;              // 0..63 (rows srow, srow+64)
  const int sch  = t & 3;
  const int csw  = ((sch ^ ((srow >> 1) & 3)) << 3);

  int gr0 = bm0 + srow;      gr0 = gr0 < N ? gr0 : N-1;
  int gr1 = bm0 + srow + 64; gr1 = gr1 < N ? gr1 : N-1;
  int gb0 = bn0 + srow;      gb0 = gb0 < O ? gb0 : O-1;
  int gb1 = bn0 + srow + 64; gb1 = gb1 < O ? gb1 : O-1;
  const u16* bA0 = A + (size_t)gr0*(size_t)ldA + csw;
  const u16* bA1 = A + (size_t)gr1*(size_t)ldA + csw;
  const u16* bA20 = SPLITA ? (A2 + ((size_t)gr0 << 10) + csw) : nullptr;
  const u16* bA21 = SPLITA ? (A2 + ((size_t)gr1 << 10) + csw) : nullptr;
  const u16* bB0 = Bmat + (size_t)gb0*(size_t)ldB + csw;
  const u16* bB1 = Bmat + (size_t)gb1*(size_t)ldB + csw;
  const int dLo = t << 3;
  const int dHi = (t << 3) + 2048;

  auto stage = [&](int j){
    const int kb = j << 5;
    const int s = j & 3;
    const u16* a0 = SPLITA ? ((kb < 1024) ? bA0 + kb : bA20 + (kb - 1024)) : bA0 + kb;
    const u16* a1 = SPLITA ? ((kb < 1024) ? bA1 + kb : bA21 + (kb - 1024)) : bA1 + kb;
    GLOAD(a0, &lA[s][dLo]);
    GLOAD(a1, &lA[s][dHi]);
    GLOAD(bB0 + kb, &lB[s][dLo]);
    GLOAD(bB1 + kb, &lB[s][dHi]);
  };

  stage(0);
  if (nkh > 1) stage(1);
  if (nkh > 2) stage(2);

  const int l15 = lane & 15;
  const int cq  = lane >> 4;
  const int soff = ((cq ^ ((l15 >> 1) & 3)) << 3);

  for (int j = 0; j < nkh; ++j){
    const int s = j & 3;
    const int cnt = 4*((j+1 < nkh) + (j+2 < nkh));
    if (cnt == 8)      { asm volatile("s_waitcnt vmcnt(8)" ::: "memory"); }
    else if (cnt == 4) { asm volatile("s_waitcnt vmcnt(4)" ::: "memory"); }
    else               { asm volatile("s_waitcnt vmcnt(0)" ::: "memory"); }
    FENCE_BARRIER();
    short8 af[4], bfv[4];
    #pragma unroll
    for (int mi=0;mi<4;mi++)
      af[mi] = *(const short8*)(&lA[s][((wr*64 + mi*16 + l15) * 32) + soff]);
    #pragma unroll
    for (int ni=0;ni<4;ni++)
      bfv[ni] = *(const short8*)(&lB[s][((wc*64 + ni*16 + l15) * 32) + soff]);
    if (j + 3 < nkh) stage(j + 3);
    __builtin_amdgcn_sched_barrier(0);
    __builtin_amdgcn_s_setprio(1);
    #pragma unroll
    for (int mi=0;mi<4;mi++)
      #pragma unroll
      for (int ni=0;ni<4;ni++)
        acc[mi][ni] = __builtin_amdgcn_mfma_f32_16x16x32_bf16(af[mi], bfv[ni], acc[mi][ni], 0, 0, 0);
    __builtin_amdgcn_s_setprio(0);
    __builtin_amdgcn_sched_barrier(0);
  }

  const int rbase = (lane >> 4) * 4;
  const int cidx = lane & 15;
  #pragma unroll
  for (int mi=0;mi<4;mi++){
    #pragma unroll
    for (int r=0;r<4;r++){
      const int n = bm0 + wr*64 + mi*16 + rbase + r;
      if (n >= N) continue;
      #pragma unroll
      for (int ni=0;ni<4;ni++){
        const int o = bn0 + wc*64 + ni*16 + cidx;
        float v = acc[mi][ni][r] + bias[o];
        if (EPI == 6){
          int b = n / NPOS;
          int pos = n - b*NPOS;
          if (pos < SS){
            Cb[(((size_t)(b*SS + pos)) << 10) + o] = f2bf(v);
          }
        } else {
          size_t idx = (size_t)n*(size_t)O + o;
          if (EPI == 0){ Cf[idx] = v; }
          else if (EPI == 1){ float sv = v/(1.f+__expf(-v)); Cb[idx] = f2bf(sv); }
          else if (EPI == 2){ Cb[idx] = f2bf(v); }
          else if (EPI == 4){ Cb[idx] = f2bf(v - bf2f(auxb[idx])); }
          else if (EPI == 5){ Cb[idx] = f2bf(1.f/(1.f+__expf(-v))); }
        }
      }
    }
  }
}

// ---------------------------------------------------------------- big NT GEMM 256x256, r6 4-slot K32 (best measured: 90.0 us)
template<int EPI>
__global__ __launch_bounds__(512, 2) void gemm_256(
    const u16* __restrict__ A, const u16* __restrict__ Bmat,
    const float* __restrict__ bias,
    float* __restrict__ Cf, u16* __restrict__ Cb,
    int N, int O, int ldA, int ldB, int klen)
{
  __shared__ __align__(16) u16 lA[4][256*32];
  __shared__ __align__(16) u16 lB[4][256*32];
  const int t = threadIdx.x;           // 0..511
  const int lane = t & 63;
  const int wid = t >> 6;              // 0..7
  const int wr = wid >> 2, wc = wid & 3;
  const int bm0 = blockIdx.x * 256;
  const int bn0 = blockIdx.y * 256;
  const int nkh = (klen >> 6) * 2;     // K-halves of 32

  f32x4 acc[8][4];
  #pragma unroll
  for (int i=0;i<8;i++)
    #pragma unroll
    for (int j=0;j<4;j++)
      acc[i][j] = (f32x4){0.f,0.f,0.f,0.f};

  const int srow = t >> 2;             // 0..127
  const int sch  = t & 3;
  const int csw  = ((sch ^ ((srow >> 1) & 3)) << 3);
  int gr0 = bm0 + srow;       gr0 = gr0 < N ? gr0 : N-1;
  int gr1 = bm0 + srow + 128; gr1 = gr1 < N ? gr1 : N-1;
  int gb0 = bn0 + srow;       gb0 = gb0 < O ? gb0 : O-1;
  int gb1 = bn0 + srow + 128; gb1 = gb1 < O ? gb1 : O-1;
  const u16* baseA0 = A    + (size_t)gr0*(size_t)ldA + csw;
  const u16* baseA1 = A    + (size_t)gr1*(size_t)ldA + csw;
  const u16* baseB0 = Bmat + (size_t)gb0*(size_t)ldB + csw;
  const u16* baseB1 = Bmat + (size_t)gb1*(size_t)ldB + csw;
  const int ldsLo = srow*32 + (sch << 3);
  const int ldsHi = (srow + 128)*32 + (sch << 3);

  auto stageA = [&](int j){
    const int kb = j << 5;
    const int s = j & 3;
    GLOAD(baseA0 + kb, &lA[s][ldsLo]);
    GLOAD(baseA1 + kb, &lA[s][ldsHi]);
  };
  auto stageB = [&](int j){
    const int kb = j << 5;
    const int s = j & 3;
    GLOAD(baseB0 + kb, &lB[s][ldsLo]);
    GLOAD(baseB1 + kb, &lB[s][ldsHi]);
  };

  stageA(0); stageB(0);
  if (nkh > 1){ stageA(1); stageB(1); }
  if (nkh > 2){ stageA(2); stageB(2); }

  const int l15 = lane & 15;
  const int cq  = lane >> 4;
  const int chS = ((cq ^ ((l15 >> 1) & 3)) << 3);

  for (int j = 0; j < nkh; ++j){
    const int s = j & 3;
    const int rem = nkh - 1 - j;
    if (rem >= 2)      { asm volatile("s_waitcnt vmcnt(8)" ::: "memory"); }
    else if (rem == 1) { asm volatile("s_waitcnt vmcnt(4)" ::: "memory"); }
    else               { asm volatile("s_waitcnt vmcnt(0)" ::: "memory"); }
    FENCE_BARRIER();
    short8 af[4], bfv[4];
    // ---- phase A: B frags + A rows 0..3, stage A-part of Kh j+3
    #pragma unroll
    for (int ni=0;ni<4;ni++)
      bfv[ni] = *(const short8*)(&lB[s][((wc*64 + ni*16 + l15) * 32) + chS]);
    #pragma unroll
    for (int mi=0;mi<4;mi++)
      af[mi] = *(const short8*)(&lA[s][((wr*128 + mi*16 + l15) * 32) + chS]);
    if (j + 3 < nkh) stageA(j + 3);
    __builtin_amdgcn_sched_barrier(0);
    __builtin_amdgcn_s_setprio(1);
    #pragma unroll
    for (int mi=0;mi<4;mi++)
      #pragma unroll
      for (int ni=0;ni<4;ni++)
        acc[mi][ni] = __builtin_amdgcn_mfma_f32_16x16x32_bf16(af[mi], bfv[ni], acc[mi][ni], 0, 0, 0);
    __builtin_amdgcn_s_setprio(0);
    __builtin_amdgcn_sched_barrier(0);
    FENCE_BARRIER();
    // ---- phase B: A rows 4..7, stage B-part of Kh j+3
    #pragma unroll
    for (int mi=0;mi<4;mi++)
      af[mi] = *(const short8*)(&lA[s][((wr*128 + (mi+4)*16 + l15) * 32) + chS]);
    if (j + 3 < nkh) stageB(j + 3);
    __builtin_amdgcn_sched_barrier(0);
    __builtin_amdgcn_s_setprio(1);
    #pragma unroll
    for (int mi=0;mi<4;mi++)
      #pragma unroll
      for (int ni=0;ni<4;ni++)
        acc[mi+4][ni] = __builtin_amdgcn_mfma_f32_16x16x32_bf16(af[mi], bfv[ni], acc[mi+4][ni], 0, 0, 0);
    __builtin_amdgcn_s_setprio(0);
    __builtin_amdgcn_sched_barrier(0);
  }

  const int rbase = (lane >> 4) * 4;
  const int cidx = lane & 15;
  #pragma unroll
  for (int mi=0;mi<8;mi++){
    #pragma unroll
    for (int r=0;r<4;r++){
      const int n = bm0 + wr*128 + mi*16 + rbase + r;
      if (n >= N) continue;
      #pragma unroll
      for (int ni=0;ni<4;ni++){
        const int o = bn0 + wc*64 + ni*16 + cidx;
        float v = acc[mi][ni][r] + bias[o];
        size_t idx = (size_t)n*(size_t)O + o;
        if (EPI == 0){ Cf[idx] = v; }
        else if (EPI == 1){ float sv = v/(1.f+__expf(-v)); Cb[idx] = f2bf(sv); }
        else if (EPI == 2){ Cb[idx] = f2bf(v); }
      }
    }
  }
}

// ---------------------------------------------------------------- TN GEMM for grad_W (reg-prefetch, swizzled LDS)
#define NSPLIT 8
__global__ __launch_bounds__(256) void gemm_tn(
    const u16* __restrict__ A, const u16* __restrict__ B,
    float* __restrict__ part0, float* __restrict__ part1)
{
  __shared__ __align__(16) u16 lA[128*64];
  __shared__ __align__(16) u16 lB[128*64];
  const int t = threadIdx.x, lane = t & 63;
  const int i0 = blockIdx.x * 128, j0 = blockIdx.y * 128, z = blockIdx.z;
  const int wid = t >> 6, wr = wid >> 1, wc = wid & 1;
  const int TILES = (NKV + 63) >> 6;                 // 129
  const int PER = (TILES + NSPLIT - 1) / NSPLIT;     // 17
  const int kt0 = z * PER;
  const int ktend = (kt0 + PER < TILES) ? (kt0 + PER) : TILES;

  f32x4 acc[4][4];
  #pragma unroll
  for (int i=0;i<4;i++)
    #pragma unroll
    for (int j=0;j<4;j++)
      acc[i][j] = (f32x4){0.f,0.f,0.f,0.f};

  const int p = t & 31;
  const int g = t >> 5;

  auto loadr = [&](int kt, short8 R[8]){
    const int n0 = kt << 6;
    const int na = n0 + 2*p, nb = na + 1;
    short8 z8 = (short8){0,0,0,0,0,0,0,0};
    R[0]=z8;R[1]=z8;R[2]=z8;R[3]=z8;R[4]=z8;R[5]=z8;R[6]=z8;R[7]=z8;
    if (na < NKV){
      const u16* ra = A + (size_t)na*1024 + i0 + g*16;
      R[0] = *(const short8*)ra; R[1] = *(const short8*)(ra+8);
      const u16* rb = B + (size_t)na*1024 + j0 + g*16;
      R[4] = *(const short8*)rb; R[5] = *(const short8*)(rb+8);
    }
    if (nb < NKV){
      const u16* ra = A + (size_t)nb*1024 + i0 + g*16;
      R[2] = *(const short8*)ra; R[3] = *(const short8*)(ra+8);
      const u16* rb = B + (size_t)nb*1024 + j0 + g*16;
      R[6] = *(const short8*)rb; R[7] = *(const short8*)(rb+8);
    }
  };

  short8 cr[8], nr[8];
  loadr(kt0, cr);

  const int pc = p >> 2, pl = p & 3;

  for (int kt = kt0; kt < ktend; ++kt){
    if (kt + 1 < ktend) loadr(kt + 1, nr);
    asm volatile("" ::: "memory");
    FENCE_BARRIER();
    u32* wA = (u32*)lA; u32* wB = (u32*)lB;
    #pragma unroll
    for (int e=0;e<8;e++){
      const int s = (pc ^ e) * 4 + pl;
      wA[(g*16 + e)*32 + s]     = ((u32)(u16)cr[0][e]) | (((u32)(u16)cr[2][e]) << 16);
      wB[(g*16 + e)*32 + s]     = ((u32)(u16)cr[4][e]) | (((u32)(u16)cr[6][e]) << 16);
    }
    #pragma unroll
    for (int e=0;e<8;e++){
      const int s = (pc ^ e) * 4 + pl;
      wA[(g*16 + 8 + e)*32 + s] = ((u32)(u16)cr[1][e]) | (((u32)(u16)cr[3][e]) << 16);
      wB[(g*16 + 8 + e)*32 + s] = ((u32)(u16)cr[5][e]) | (((u32)(u16)cr[7][e]) << 16);
    }
    asm volatile("s_waitcnt lgkmcnt(0)" ::: "memory");
    FENCE_BARRIER();
    const int l15 = lane & 15;
    const int rx = l15 & 7;
    const int cq = lane >> 4;
    #pragma unroll
    for (int kk=0;kk<2;kk++){
      const int soff = (((kk*4 + cq) ^ rx) << 3);
      short8 af[4], bfv[4];
      #pragma unroll
      for (int mi=0;mi<4;mi++)
        af[mi] = *(const short8*)(lA + ((wr*64 + mi*16 + l15) << 6) + soff);
      #pragma unroll
      for (int ni=0;ni<4;ni++)
        bfv[ni] = *(const short8*)(lB + ((wc*64 + ni*16 + l15) << 6) + soff);
      #pragma unroll
      for (int mi=0;mi<4;mi++)
        #pragma unroll
        for (int ni=0;ni<4;ni++)
          acc[mi][ni] = __builtin_amdgcn_mfma_f32_16x16x32_bf16(af[mi], bfv[ni], acc[mi][ni], 0, 0, 0);
    }
    #pragma unroll
    for (int e=0;e<8;e++) cr[e] = nr[e];
  }

  float* dst = (z < 4) ? (part0 + ((size_t)z << 20)) : (part1 + ((size_t)(z-4) << 20));
  const int rbase = (lane >> 4) * 4;
  const int cidx = lane & 15;
  #pragma unroll
  for (int mi=0;mi<4;mi++)
    #pragma unroll
    for (int r=0;r<4;r++){
      const int i = i0 + wr*64 + mi*16 + rbase + r;
      #pragma unroll
      for (int ni=0;ni<4;ni++){
        const int j = j0 + wc*64 + ni*16 + cidx;
        dst[((size_t)i << 10) + j] = acc[mi][ni][r];
      }
    }
}

// ---------------------------------------------------------------- W_new (8 partial slices)
__global__ __launch_bounds__(256) void wnew_k(const float* __restrict__ part0,
                                              const float* __restrict__ part1,
                                              const float* __restrict__ memW,
                                              const float* __restrict__ fg,
                                              const float* __restrict__ lr,
                                              u16* __restrict__ out)
{
  int i = blockIdx.x*256 + threadIdx.x;
  float s = part0[i] + part0[i + (1<<20)] + part0[i + (2<<20)] + part0[i + (3<<20)]
          + part1[i] + part1[i + (1<<20)] + part1[i + (2<<20)] + part1[i + (3<<20)];
  const float scale = 2.f / ((float)NKV * 1024.f);
  float v = (1.f - fg[0])*memW[i] + lr[0]*scale*s;
  out[i] = f2bf(v);
}

// ---------------------------------------------------------------- x2 = LN(x1 + gate*x1 + (1-gate)*mo)
__global__ __launch_bounds__(256) void ln_gate(
    const u16* __restrict__ x1b, const u16* __restrict__ gateb,
    const u16* __restrict__ mob, const float* __restrict__ g2,
    const float* __restrict__ be2, u16* __restrict__ x2b)
{
  const int n = blockIdx.x;
  const int t = threadIdx.x, lane = t & 63, w = t >> 6;
  const size_t rb = (size_t)n << 8;
  ushort4 xa = ((const ushort4*)x1b)[rb+t];
  ushort4 ga = ((const ushort4*)gateb)[rb+t];
  ushort4 ma = ((const ushort4*)mob)[rb+t];
  float a0=bf2f(xa.x),a1=bf2f(xa.y),a2=bf2f(xa.z),a3=bf2f(xa.w);
  float g0=bf2f(ga.x),g1v=bf2f(ga.y),g2v=bf2f(ga.z),g3v=bf2f(ga.w);
  float m0=bf2f(ma.x),m1=bf2f(ma.y),m2=bf2f(ma.z),m3=bf2f(ma.w);
  float y0 = a0 + g0*a0 + (1.f-g0)*m0;
  float y1 = a1 + g1v*a1 + (1.f-g1v)*m1;
  float y2 = a2 + g2v*a2 + (1.f-g2v)*m2;
  float y3 = a3 + g3v*a3 + (1.f-g3v)*m3;
  float s1 = y0+y1+y2+y3;
  float s2 = y0*y0+y1*y1+y2*y2+y3*y3;
  #pragma unroll
  for (int off=32; off; off>>=1){ s1 += __shfl_xor(s1, off, 64); s2 += __shfl_xor(s2, off, 64); }
  __shared__ float rsh[8];
  if (lane == 0){ rsh[w] = s1; rsh[4+w] = s2; }
  __syncthreads();
  float S1 = rsh[0]+rsh[1]+rsh[2]+rsh[3];
  float S2 = rsh[4]+rsh[5]+rsh[6]+rsh[7];
  float mean = S1 * (1.f/1024.f);
  float var  = S2 * (1.f/1024.f) - mean*mean;
  float rstd = 1.f/sqrtf(var + 1e-5f);
  float4 gv = ((const float4*)g2)[t];
  float4 bv = ((const float4*)be2)[t];
  ushort4 ob;
  ob.x = f2bf((y0-mean)*rstd*gv.x + bv.x);
  ob.y = f2bf((y1-mean)*rstd*gv.y + bv.y);
  ob.z = f2bf((y2-mean)*rstd*gv.z + bv.z);
  ob.w = f2bf((y3-mean)*rstd*gv.w + bv.w);
  ((ushort4*)x2b)[rb + t] = ob;
}

// ---------------------------------------------------------------- out = LN(x2 + ff2) (ff2 in d_out, in-place)
__global__ __launch_bounds__(256) void ln_final(
    const u16* __restrict__ x2b, const float* __restrict__ g3,
    const float* __restrict__ be3, float* __restrict__ out)
{
  const int n = blockIdx.x;
  const int t = threadIdx.x, lane = t & 63, w = t >> 6;
  const size_t rb = (size_t)n << 8;
  ushort4 xa = ((const ushort4*)x2b)[rb+t];
  float4 f = ((const float4*)out)[rb+t];
  float y0 = bf2f(xa.x)+f.x, y1 = bf2f(xa.y)+f.y, y2 = bf2f(xa.z)+f.z, y3 = bf2f(xa.w)+f.w;
  float s1 = y0+y1+y2+y3;
  float s2 = y0*y0+y1*y1+y2*y2+y3*y3;
  #pragma unroll
  for (int off=32; off; off>>=1){ s1 += __shfl_xor(s1, off, 64); s2 += __shfl_xor(s2, off, 64); }
  __shared__ float rsh[8];
  if (lane == 0){ rsh[w] = s1; rsh[4+w] = s2; }
  __syncthreads();
  float S1 = rsh[0]+rsh[1]+rsh[2]+rsh[3];
  float S2 = rsh[4]+rsh[5]+rsh[6]+rsh[7];
  float mean = S1 * (1.f/1024.f);
  float var  = S2 * (1.f/1024.f) - mean*mean;
  float rstd = 1.f/sqrtf(var + 1e-5f);
  float4 gv = ((const float4*)g3)[t];
  float4 bv = ((const float4*)be3)[t];
  float4 o;
  o.x = (y0-mean)*rstd*gv.x + bv.x;
  o.y = (y1-mean)*rstd*gv.y + bv.y;
  o.z = (y2-mean)*rstd*gv.z + bv.z;
  o.w = (y3-mean)*rstd*gv.w + bv.w;
  ((float4*)out)[rb + t] = o;
}

// ================================================================ host
extern "C" void kernel_launch(void* const* d_in, const int* in_sizes, int n_in,
                              void* d_out, int out_size, void* d_ws, size_t ws_size,
                              hipStream_t stream)
{
  const float* x    = (const float*)d_in[0];
  const float* memW = (const float*)d_in[1];
  const float* memb = (const float*)d_in[2];
  const float* P    = (const float*)d_in[3];
  const float* Wi   = (const float*)d_in[4];
  const float* bi   = (const float*)d_in[5];
  const float* Wl1  = (const float*)d_in[6];
  const float* bl1  = (const float*)d_in[7];
  const float* Wl2  = (const float*)d_in[8];
  const float* bl2  = (const float*)d_in[9];
  const float* Wo   = (const float*)d_in[10];
  const float* bo   = (const float*)d_in[11];
  const float* fg   = (const float*)d_in[12];
  const float* lr   = (const float*)d_in[13];
  const float* Wg   = (const float*)d_in[14];
  const float* bg   = (const float*)d_in[15];
  const float* W1   = (const float*)d_in[16];
  const float* b1   = (const float*)d_in[17];
  const float* W2   = (const float*)d_in[18];
  const float* b2   = (const float*)d_in[19];
  const float* g1   = (const float*)d_in[20];
  const float* be1  = (const float*)d_in[21];
  const float* g2   = (const float*)d_in[22];
  const float* be2  = (const float*)d_in[23];
  const float* g3   = (const float*)d_in[24];
  const float* be3  = (const float*)d_in[25];
  float* out = (float*)d_out;

  const size_t SZ_TOK = (size_t)NTOK*1024*2;
  const size_t SZ_KV  = (size_t)NKV*1024*2;
  char* base = (char*)d_ws;
  size_t off = 0;
  auto alloc = [&](size_t bytes) -> char* {
    char* p = base + off;
    off += (bytes + 255) & ~(size_t)255;
    return p;
  };
  u16* x1b   = (u16*)alloc(SZ_TOK);
  u16* knb   = (u16*)alloc(SZ_KV);
  u16* h1b   = (u16*)alloc(SZ_KV);
  u16* hddb  = (u16*)alloc(SZ_KV);
  u16* kpb   = (u16*)alloc(SZ_KV);
  u16* wnewb = (u16*)alloc((size_t)1024*1024*2);
  u16* WiB   = (u16*)alloc((size_t)1024*1024*2);
  u16* Wl1B  = (u16*)alloc((size_t)1024*1024*2);
  u16* Wl2B  = (u16*)alloc((size_t)1024*1024*2);
  u16* memWB = (u16*)alloc((size_t)1024*1024*2);
  u16* WoB   = (u16*)alloc((size_t)1024*1024*2);
  u16* WgB   = (u16*)alloc((size_t)1024*2048*2);
  u16* W1B   = (u16*)alloc((size_t)4096*1024*2);
  u16* W2B   = (u16*)alloc((size_t)1024*4096*2);
  if (ws_size < off) return;   // diagnostic guard

  // aliases (lifetimes strictly sequential):
  u16*   diffb   = knb;            // knb dead after kp GEMM
  float* part0   = (float*)kpb;    // kpb dead after diff GEMM; grad slices 0-3
  float* part1   = (float*)h1b;    // h1b dead after hdd GEMM; grad slices 4-7 (consumed by wnew before mo writes mob)
  u16*   memoutb = knb;            // diffb dead after grad GEMM
  u16*   mob     = h1b;            // part1 dead after wnew_k
  u16*   gateb   = hddb;           // hddb dead after mo GEMM
  u16*   x2b     = kpb;            // part0 dead after wnew_k
  u16*   ff1b    = x1b;            // spans x1b+knb+h1b+hddb (67.2 MiB >= 64 MiB)

  cvt_all<<<2048, 256, 0, stream>>>(
      (const float4*)Wi, (const float4*)Wl1, (const float4*)Wl2, (const float4*)memW,
      (const float4*)Wo, (const float4*)Wg, (const float4*)W1, (const float4*)W2,
      (ushort4*)WiB, (ushort4*)Wl1B, (ushort4*)Wl2B, (ushort4*)memWB,
      (ushort4*)WoB, (ushort4*)WgB, (ushort4*)W1B, (ushort4*)W2B);

  attn_kv<<<NATTB + NKVB, 256, 0, stream>>>(x, P, g1, be1, x1b, knb);

  dim3 gkv(65, 8, 1);
  gemm_nt<2,0><<<gkv, 256, 0, stream>>>(knb, nullptr, WiB, bi, nullptr, nullptr, kpb, NKV, 1024, 1024, 1024, 1024);
  gemm_nt<1,0><<<gkv, 256, 0, stream>>>(kpb, nullptr, Wl1B, bl1, nullptr, nullptr, h1b, NKV, 1024, 1024, 1024, 1024);
  gemm_nt<1,0><<<gkv, 256, 0, stream>>>(h1b, nullptr, Wl2B, bl2, nullptr, nullptr, hddb, NKV, 1024, 1024, 1024, 1024);
  gemm_nt<4,0><<<gkv, 256, 0, stream>>>(hddb, nullptr, memWB, memb, kpb, nullptr, diffb, NKV, 1024, 1024, 1024, 1024);
  gemm_tn<<<dim3(8, 8, NSPLIT), 256, 0, stream>>>(diffb, hddb, part0, part1);
  wnew_k<<<4096, 256, 0, stream>>>(part0, part1, memW, fg, lr, wnewb);
  gemm_nt<2,0><<<gkv, 256, 0, stream>>>(hddb, nullptr, wnewb, memb, nullptr, nullptr, memoutb, NKV, 1024, 1024, 1024, 1024);
  gemm_nt<6,0><<<gkv, 256, 0, stream>>>(memoutb, nullptr, WoB, bo, nullptr, nullptr, mob, NKV, 1024, 1024, 1024, 1024);
  gemm_nt<5,1><<<dim3(64, 8, 1), 256, 0, stream>>>(x1b, mob, WgB, bg, nullptr, nullptr, gateb, NTOK, 1024, 1024, 2048, 2048);
  ln_gate<<<NTOK, 256, 0, stream>>>(x1b, gateb, mob, g2, be2, x2b);
  // ff1 = silu(x2 @ W1.T + b1) : 256x256 r6 4-slot kernel (512 blocks)
  gemm_256<1><<<dim3(32, 16, 1), 512, 0, stream>>>(x2b, W1B, b1, nullptr, ff1b, NTOK, 4096, 1024, 1024, 1024);
  // ff2 = ff1 @ W2.T + b2 -> f32 directly into d_out (128^2, 512 blocks, full chip)
  gemm_nt<0,0><<<dim3(64, 8, 1), 256, 0, stream>>>(ff1b, nullptr, W2B, b2, nullptr, out, nullptr, NTOK, 1024, 4096, 4096, 4096);
  ln_final<<<NTOK, 256, 0, stream>>>(x2b, g3, be3, out);
}

// Round 15
// 599.262 us; speedup vs baseline: 1.0145x; 1.0006x over previous
//
#include <hip/hip_runtime.h>
#include <hip/hip_bf16.h>

#define WIN 16
#define SLOTS 10
#define SS 4096
#define NTOK 8192
#define NKV 8212
#define NPOS 4106
#define NATTB 2048
#define NKVB 2053
#define CVT_N 3932160

typedef unsigned short u16;
typedef unsigned int u32;
typedef __attribute__((ext_vector_type(8))) short short8;
typedef __attribute__((ext_vector_type(4))) float f32x4;

__device__ __forceinline__ u16 f2bf(float f){
  union { float f; u32 u; } a; a.f = f;
  u32 r = (a.u + 0x7fff + ((a.u >> 16) & 1)) >> 16;
  return (u16)r;
}
__device__ __forceinline__ float bf2f(u16 v){
  union { u32 u; float f; } a; a.u = ((u32)v) << 16;
  return a.f;
}
__device__ __forceinline__ float wred(float v){
  #pragma unroll
  for (int off=32; off; off>>=1) v += __shfl_xor(v, off, 64);
  return v;
}

#define GLOAD(gp, lp) __builtin_amdgcn_global_load_lds( \
    (const __attribute__((address_space(1))) void*)(gp), \
    (__attribute__((address_space(3))) void*)(lp), 16, 0, 0)

#define FENCE_BARRIER() do { \
    __builtin_amdgcn_sched_barrier(0); \
    __builtin_amdgcn_s_barrier(); \
    __builtin_amdgcn_sched_barrier(0); \
  } while(0)

// ---------------------------------------------------------------- fused weight cvt f32->bf16 (grid-stride)
__global__ __launch_bounds__(256) void cvt_all(
    const float4* __restrict__ s0, const float4* __restrict__ s1,
    const float4* __restrict__ s2, const float4* __restrict__ s3,
    const float4* __restrict__ s4, const float4* __restrict__ s5,
    const float4* __restrict__ s6, const float4* __restrict__ s7,
    ushort4* __restrict__ d0, ushort4* __restrict__ d1,
    ushort4* __restrict__ d2, ushort4* __restrict__ d3,
    ushort4* __restrict__ d4, ushort4* __restrict__ d5,
    ushort4* __restrict__ d6, ushort4* __restrict__ d7)
{
  for (int i = blockIdx.x * 256 + threadIdx.x; i < CVT_N; i += 2048*256){
    const float4* s; ushort4* d; int base;
    if      (i <  262144){ s=s0; d=d0; base=0; }
    else if (i <  524288){ s=s1; d=d1; base=262144; }
    else if (i <  786432){ s=s2; d=d2; base=524288; }
    else if (i < 1048576){ s=s3; d=d3; base=786432; }
    else if (i < 1310720){ s=s4; d=d4; base=1048576; }
    else if (i < 1835008){ s=s5; d=d5; base=1310720; }
    else if (i < 2883584){ s=s6; d=d6; base=1835008; }
    else                 { s=s7; d=d7; base=2883584; }
    float4 v = s[i - base];
    ushort4 o; o.x=f2bf(v.x); o.y=f2bf(v.y); o.z=f2bf(v.z); o.w=f2bf(v.w);
    d[i - base] = o;
  }
}

// ---------------------------------------------------------------- block-tiled attn+LN1 / wave-per-row kv-norm
// blocks [0, NATTB): 4 consecutive tokens; union window (20 rows) staged in LDS once.
// blocks [NATTB, NATTB+NKVB): 4 kv rows each (one wave per row).
__global__ __launch_bounds__(256) void attn_kv(
    const float* __restrict__ x, const float* __restrict__ P,
    const float* __restrict__ g1, const float* __restrict__ be1,
    u16* __restrict__ x1b, u16* __restrict__ kn)
{
  __shared__ float winbuf[20][1024];
  const int blk = blockIdx.x;
  const int t = threadIdx.x, lane = t & 63, wid = t >> 6;
  if (blk >= NATTB){
    const int r = (blk - NATTB)*4 + wid;
    if (r >= NKV) return;
    const int b = r / NPOS;
    const int pos = r - b*NPOS;
    const float4* src = (const float4*)((pos < SS) ? (x + (((size_t)b*SS + pos) << 10))
                                                   : (P + ((size_t)(pos - SS) << 10)));
    float4 v[4];
    float ss = 0.f;
    #pragma unroll
    for (int e=0;e<4;e++){
      v[e] = src[(lane<<2)+e];
      ss += v[e].x*v[e].x + v[e].y*v[e].y + v[e].z*v[e].z + v[e].w*v[e].w;
    }
    ss = wred(ss);
    float inv = 1.f / fmaxf(sqrtf(ss), 1e-12f);
    ushort4* dst = (ushort4*)kn + ((size_t)r << 8);
    #pragma unroll
    for (int e=0;e<4;e++){
      ushort4 o; o.x=f2bf(v[e].x*inv); o.y=f2bf(v[e].y*inv); o.z=f2bf(v[e].z*inv); o.w=f2bf(v[e].w*inv);
      dst[(lane<<2)+e] = o;
    }
    return;
  }
  // ---- attention + LN1: block = tokens t0..t0+3 (same batch; 4096%4==0)
  const int t0 = blk*4;
  const int b = t0 >> 12, s0 = t0 & 4095;
  const float* xb = x + ((size_t)b << 22);
  // stage union window rows s0-16 .. s0+3 (clamped; clamped rows never read)
  #pragma unroll
  for (int k = 0; k < 20; ++k){
    int idx = t + (k << 8);
    int r = idx >> 8, c = idx & 255;
    int gs = s0 - 16 + r;
    int gsc = gs < 0 ? 0 : gs;
    ((float4*)winbuf[r])[c] = ((const float4*)(xb + ((size_t)gsc << 10)))[c];
  }
  __syncthreads();

  const int s = s0 + wid;              // this wave's token
  // lane-contiguous column mapping: float4 idx = lane + e*64 (conflict-free LDS)
  float4 q[4];
  #pragma unroll
  for (int e=0;e<4;e++) q[e] = ((const float4*)winbuf[16+wid])[lane + (e<<6)];

  const int j0 = (s >= WIN) ? 0 : (WIN - s);
  float m = -3.0e38f, l = 0.f;
  float4 o[4];
  #pragma unroll
  for (int e=0;e<4;e++) o[e] = make_float4(0.f,0.f,0.f,0.f);

  for (int j = j0; j < 17; ++j){
    const float4* kp_ = (const float4*)winbuf[wid + j];
    float4 kk[4];
    float dp = 0.f;
    #pragma unroll
    for (int e=0;e<4;e++){
      kk[e] = kp_[lane + (e<<6)];
      dp += q[e].x*kk[e].x + q[e].y*kk[e].y + q[e].z*kk[e].z + q[e].w*kk[e].w;
    }
    dp = wred(dp) * 0.03125f;
    float mn = fmaxf(m, dp);
    float sc = __expf(m - mn);
    float e_ = __expf(dp - mn);
    l = l*sc + e_;
    #pragma unroll
    for (int e=0;e<4;e++){
      o[e].x = o[e].x*sc + e_*kk[e].x;
      o[e].y = o[e].y*sc + e_*kk[e].y;
      o[e].z = o[e].z*sc + e_*kk[e].z;
      o[e].w = o[e].w*sc + e_*kk[e].w;
    }
    m = mn;
  }
  const float il = 1.f / l;
  float s1 = 0.f, s2 = 0.f;
  float4 y[4];
  #pragma unroll
  for (int e=0;e<4;e++){
    y[e].x = q[e].x + o[e].x*il;
    y[e].y = q[e].y + o[e].y*il;
    y[e].z = q[e].z + o[e].z*il;
    y[e].w = q[e].w + o[e].w*il;
    s1 += y[e].x + y[e].y + y[e].z + y[e].w;
    s2 += y[e].x*y[e].x + y[e].y*y[e].y + y[e].z*y[e].z + y[e].w*y[e].w;
  }
  s1 = wred(s1); s2 = wred(s2);
  float mean = s1 * (1.f/1024.f);
  float var  = s2 * (1.f/1024.f) - mean*mean;
  float rstd = 1.f/sqrtf(var + 1e-5f);
  const int n = t0 + wid;
  ushort4* dst = (ushort4*)x1b + ((size_t)n << 8);
  #pragma unroll
  for (int e=0;e<4;e++){
    const int ci = lane + (e<<6);
    float4 gv = ((const float4*)g1)[ci];
    float4 bv = ((const float4*)be1)[ci];
    ushort4 ob;
    ob.x = f2bf((y[e].x-mean)*rstd*gv.x + bv.x);
    ob.y = f2bf((y[e].y-mean)*rstd*gv.y + bv.y);
    ob.z = f2bf((y[e].z-mean)*rstd*gv.z + bv.z);
    ob.w = f2bf((y[e].w-mean)*rstd*gv.w + bv.w);
    dst[ci] = ob;
  }
}

// ---------------------------------------------------------------- generic NT GEMM 128x128, 4-slot K32 pipeline
template<int EPI, int SPLITA>
__global__ __launch_bounds__(256) void gemm_nt(
    const u16* __restrict__ A, const u16* __restrict__ A2,
    const u16* __restrict__ Bmat, const float* __restrict__ bias,
    const u16* __restrict__ auxb,
    float* __restrict__ Cf, u16* __restrict__ Cb,
    int N, int O, int ldA, int ldB, int klen)
{
  __shared__ __align__(16) u16 lA[4][128*32];
  __shared__ __align__(16) u16 lB[4][128*32];
  const int t = threadIdx.x;
  const int lane = t & 63;
  const int bm0 = blockIdx.x * 128;
  const int bn0 = blockIdx.y * 128;
  const int wid = t >> 6;
  const int wr = wid >> 1, wc = wid & 1;
  const int nkh = klen >> 5;            // K-halves of 32

  f32x4 acc[4][4];
  #pragma unroll
  for (int i=0;i<4;i++)
    #pragma unroll
    for (int j=0;j<4;j++)
      acc[i][j] = (f32x4){0.f,0.f,0.f,0.f};

  const int srow = t >> 2;              // 0..63 (rows srow, srow+64)
  const int sch  = t & 3;
  const int csw  = ((sch ^ ((srow >> 1) & 3)) << 3);

  int gr0 = bm0 + srow;      gr0 = gr0 < N ? gr0 : N-1;
  int gr1 = bm0 + srow + 64; gr1 = gr1 < N ? gr1 : N-1;
  int gb0 = bn0 + srow;      gb0 = gb0 < O ? gb0 : O-1;
  int gb1 = bn0 + srow + 64; gb1 = gb1 < O ? gb1 : O-1;
  const u16* bA0 = A + (size_t)gr0*(size_t)ldA + csw;
  const u16* bA1 = A + (size_t)gr1*(size_t)ldA + csw;
  const u16* bA20 = SPLITA ? (A2 + ((size_t)gr0 << 10) + csw) : nullptr;
  const u16* bA21 = SPLITA ? (A2 + ((size_t)gr1 << 10) + csw) : nullptr;
  const u16* bB0 = Bmat + (size_t)gb0*(size_t)ldB + csw;
  const u16* bB1 = Bmat + (size_t)gb1*(size_t)ldB + csw;
  const int dLo = t << 3;
  const int dHi = (t << 3) + 2048;

  auto stage = [&](int j){
    const int kb = j << 5;
    const int s = j & 3;
    const u16* a0 = SPLITA ? ((kb < 1024) ? bA0 + kb : bA20 + (kb - 1024)) : bA0 + kb;
    const u16* a1 = SPLITA ? ((kb < 1024) ? bA1 + kb : bA21 + (kb - 1024)) : bA1 + kb;
    GLOAD(a0, &lA[s][dLo]);
    GLOAD(a1, &lA[s][dHi]);
    GLOAD(bB0 + kb, &lB[s][dLo]);
    GLOAD(bB1 + kb, &lB[s][dHi]);
  };

  stage(0);
  if (nkh > 1) stage(1);
  if (nkh > 2) stage(2);

  const int l15 = lane & 15;
  const int cq  = lane >> 4;
  const int soff = ((cq ^ ((l15 >> 1) & 3)) << 3);

  for (int j = 0; j < nkh; ++j){
    const int s = j & 3;
    const int cnt = 4*((j+1 < nkh) + (j+2 < nkh));
    if (cnt == 8)      { asm volatile("s_waitcnt vmcnt(8)" ::: "memory"); }
    else if (cnt == 4) { asm volatile("s_waitcnt vmcnt(4)" ::: "memory"); }
    else               { asm volatile("s_waitcnt vmcnt(0)" ::: "memory"); }
    FENCE_BARRIER();
    short8 af[4], bfv[4];
    #pragma unroll
    for (int mi=0;mi<4;mi++)
      af[mi] = *(const short8*)(&lA[s][((wr*64 + mi*16 + l15) * 32) + soff]);
    #pragma unroll
    for (int ni=0;ni<4;ni++)
      bfv[ni] = *(const short8*)(&lB[s][((wc*64 + ni*16 + l15) * 32) + soff]);
    if (j + 3 < nkh) stage(j + 3);
    __builtin_amdgcn_sched_barrier(0);
    __builtin_amdgcn_s_setprio(1);
    #pragma unroll
    for (int mi=0;mi<4;mi++)
      #pragma unroll
      for (int ni=0;ni<4;ni++)
        acc[mi][ni] = __builtin_amdgcn_mfma_f32_16x16x32_bf16(af[mi], bfv[ni], acc[mi][ni], 0, 0, 0);
    __builtin_amdgcn_s_setprio(0);
    __builtin_amdgcn_sched_barrier(0);
  }

  const int rbase = (lane >> 4) * 4;
  const int cidx = lane & 15;
  #pragma unroll
  for (int mi=0;mi<4;mi++){
    #pragma unroll
    for (int r=0;r<4;r++){
      const int n = bm0 + wr*64 + mi*16 + rbase + r;
      if (n >= N) continue;
      #pragma unroll
      for (int ni=0;ni<4;ni++){
        const int o = bn0 + wc*64 + ni*16 + cidx;
        float v = acc[mi][ni][r] + bias[o];
        if (EPI == 6){
          int b = n / NPOS;
          int pos = n - b*NPOS;
          if (pos < SS){
            Cb[(((size_t)(b*SS + pos)) << 10) + o] = f2bf(v);
          }
        } else {
          size_t idx = (size_t)n*(size_t)O + o;
          if (EPI == 0){ Cf[idx] = v; }
          else if (EPI == 1){ float sv = v/(1.f+__expf(-v)); Cb[idx] = f2bf(sv); }
          else if (EPI == 2){ Cb[idx] = f2bf(v); }
          else if (EPI == 4){ Cb[idx] = f2bf(v - bf2f(auxb[idx])); }
          else if (EPI == 5){ Cb[idx] = f2bf(1.f/(1.f+__expf(-v))); }
        }
      }
    }
  }
}

// ---------------------------------------------------------------- big NT GEMM 256x256, r6 4-slot K32 (best measured: 90.0 us)
template<int EPI>
__global__ __launch_bounds__(512, 2) void gemm_256(
    const u16* __restrict__ A, const u16* __restrict__ Bmat,
    const float* __restrict__ bias,
    float* __restrict__ Cf, u16* __restrict__ Cb,
    int N, int O, int ldA, int ldB, int klen)
{
  __shared__ __align__(16) u16 lA[4][256*32];
  __shared__ __align__(16) u16 lB[4][256*32];
  const int t = threadIdx.x;           // 0..511
  const int lane = t & 63;
  const int wid = t >> 6;              // 0..7
  const int wr = wid >> 2, wc = wid & 3;
  const int bm0 = blockIdx.x * 256;
  const int bn0 = blockIdx.y * 256;
  const int nkh = (klen >> 6) * 2;     // K-halves of 32

  f32x4 acc[8][4];
  #pragma unroll
  for (int i=0;i<8;i++)
    #pragma unroll
    for (int j=0;j<4;j++)
      acc[i][j] = (f32x4){0.f,0.f,0.f,0.f};

  const int srow = t >> 2;             // 0..127
  const int sch  = t & 3;
  const int csw  = ((sch ^ ((srow >> 1) & 3)) << 3);
  int gr0 = bm0 + srow;       gr0 = gr0 < N ? gr0 : N-1;
  int gr1 = bm0 + srow + 128; gr1 = gr1 < N ? gr1 : N-1;
  int gb0 = bn0 + srow;       gb0 = gb0 < O ? gb0 : O-1;
  int gb1 = bn0 + srow + 128; gb1 = gb1 < O ? gb1 : O-1;
  const u16* baseA0 = A    + (size_t)gr0*(size_t)ldA + csw;
  const u16* baseA1 = A    + (size_t)gr1*(size_t)ldA + csw;
  const u16* baseB0 = Bmat + (size_t)gb0*(size_t)ldB + csw;
  const u16* baseB1 = Bmat + (size_t)gb1*(size_t)ldB + csw;
  const int ldsLo = srow*32 + (sch << 3);
  const int ldsHi = (srow + 128)*32 + (sch << 3);

  auto stageA = [&](int j){
    const int kb = j << 5;
    const int s = j & 3;
    GLOAD(baseA0 + kb, &lA[s][ldsLo]);
    GLOAD(baseA1 + kb, &lA[s][ldsHi]);
  };
  auto stageB = [&](int j){
    const int kb = j << 5;
    const int s = j & 3;
    GLOAD(baseB0 + kb, &lB[s][ldsLo]);
    GLOAD(baseB1 + kb, &lB[s][ldsHi]);
  };

  stageA(0); stageB(0);
  if (nkh > 1){ stageA(1); stageB(1); }
  if (nkh > 2){ stageA(2); stageB(2); }

  const int l15 = lane & 15;
  const int cq  = lane >> 4;
  const int chS = ((cq ^ ((l15 >> 1) & 3)) << 3);

  for (int j = 0; j < nkh; ++j){
    const int s = j & 3;
    const int rem = nkh - 1 - j;
    if (rem >= 2)      { asm volatile("s_waitcnt vmcnt(8)" ::: "memory"); }
    else if (rem == 1) { asm volatile("s_waitcnt vmcnt(4)" ::: "memory"); }
    else               { asm volatile("s_waitcnt vmcnt(0)" ::: "memory"); }
    FENCE_BARRIER();
    short8 af[4], bfv[4];
    // ---- phase A: B frags + A rows 0..3, stage A-part of Kh j+3
    #pragma unroll
    for (int ni=0;ni<4;ni++)
      bfv[ni] = *(const short8*)(&lB[s][((wc*64 + ni*16 + l15) * 32) + chS]);
    #pragma unroll
    for (int mi=0;mi<4;mi++)
      af[mi] = *(const short8*)(&lA[s][((wr*128 + mi*16 + l15) * 32) + chS]);
    if (j + 3 < nkh) stageA(j + 3);
    __builtin_amdgcn_sched_barrier(0);
    __builtin_amdgcn_s_setprio(1);
    #pragma unroll
    for (int mi=0;mi<4;mi++)
      #pragma unroll
      for (int ni=0;ni<4;ni++)
        acc[mi][ni] = __builtin_amdgcn_mfma_f32_16x16x32_bf16(af[mi], bfv[ni], acc[mi][ni], 0, 0, 0);
    __builtin_amdgcn_s_setprio(0);
    __builtin_amdgcn_sched_barrier(0);
    FENCE_BARRIER();
    // ---- phase B: A rows 4..7, stage B-part of Kh j+3
    #pragma unroll
    for (int mi=0;mi<4;mi++)
      af[mi] = *(const short8*)(&lA[s][((wr*128 + (mi+4)*16 + l15) * 32) + chS]);
    if (j + 3 < nkh) stageB(j + 3);
    __builtin_amdgcn_sched_barrier(0);
    __builtin_amdgcn_s_setprio(1);
    #pragma unroll
    for (int mi=0;mi<4;mi++)
      #pragma unroll
      for (int ni=0;ni<4;ni++)
        acc[mi+4][ni] = __builtin_amdgcn_mfma_f32_16x16x32_bf16(af[mi], bfv[ni], acc[mi+4][ni], 0, 0, 0);
    __builtin_amdgcn_s_setprio(0);
    __builtin_amdgcn_sched_barrier(0);
  }

  const int rbase = (lane >> 4) * 4;
  const int cidx = lane & 15;
  #pragma unroll
  for (int mi=0;mi<8;mi++){
    #pragma unroll
    for (int r=0;r<4;r++){
      const int n = bm0 + wr*128 + mi*16 + rbase + r;
      if (n >= N) continue;
      #pragma unroll
      for (int ni=0;ni<4;ni++){
        const int o = bn0 + wc*64 + ni*16 + cidx;
        float v = acc[mi][ni][r] + bias[o];
        size_t idx = (size_t)n*(size_t)O + o;
        if (EPI == 0){ Cf[idx] = v; }
        else if (EPI == 1){ float sv = v/(1.f+__expf(-v)); Cb[idx] = f2bf(sv); }
        else if (EPI == 2){ Cb[idx] = f2bf(v); }
      }
    }
  }
}

// ---------------------------------------------------------------- TN GEMM for grad_W (reg-prefetch, swizzled LDS)
#define NSPLIT 8
__global__ __launch_bounds__(256) void gemm_tn(
    const u16* __restrict__ A, const u16* __restrict__ B,
    float* __restrict__ part0, float* __restrict__ part1)
{
  __shared__ __align__(16) u16 lA[128*64];
  __shared__ __align__(16) u16 lB[128*64];
  const int t = threadIdx.x, lane = t & 63;
  const int i0 = blockIdx.x * 128, j0 = blockIdx.y * 128, z = blockIdx.z;
  const int wid = t >> 6, wr = wid >> 1, wc = wid & 1;
  const int TILES = (NKV + 63) >> 6;                 // 129
  const int PER = (TILES + NSPLIT - 1) / NSPLIT;     // 17
  const int kt0 = z * PER;
  const int ktend = (kt0 + PER < TILES) ? (kt0 + PER) : TILES;

  f32x4 acc[4][4];
  #pragma unroll
  for (int i=0;i<4;i++)
    #pragma unroll
    for (int j=0;j<4;j++)
      acc[i][j] = (f32x4){0.f,0.f,0.f,0.f};

  const int p = t & 31;
  const int g = t >> 5;

  auto loadr = [&](int kt, short8 R[8]){
    const int n0 = kt << 6;
    const int na = n0 + 2*p, nb = na + 1;
    short8 z8 = (short8){0,0,0,0,0,0,0,0};
    R[0]=z8;R[1]=z8;R[2]=z8;R[3]=z8;R[4]=z8;R[5]=z8;R[6]=z8;R[7]=z8;
    if (na < NKV){
      const u16* ra = A + (size_t)na*1024 + i0 + g*16;
      R[0] = *(const short8*)ra; R[1] = *(const short8*)(ra+8);
      const u16* rb = B + (size_t)na*1024 + j0 + g*16;
      R[4] = *(const short8*)rb; R[5] = *(const short8*)(rb+8);
    }
    if (nb < NKV){
      const u16* ra = A + (size_t)nb*1024 + i0 + g*16;
      R[2] = *(const short8*)ra; R[3] = *(const short8*)(ra+8);
      const u16* rb = B + (size_t)nb*1024 + j0 + g*16;
      R[6] = *(const short8*)rb; R[7] = *(const short8*)(rb+8);
    }
  };

  short8 cr[8], nr[8];
  loadr(kt0, cr);

  const int pc = p >> 2, pl = p & 3;

  for (int kt = kt0; kt < ktend; ++kt){
    if (kt + 1 < ktend) loadr(kt + 1, nr);
    asm volatile("" ::: "memory");
    FENCE_BARRIER();
    u32* wA = (u32*)lA; u32* wB = (u32*)lB;
    #pragma unroll
    for (int e=0;e<8;e++){
      const int s = (pc ^ e) * 4 + pl;
      wA[(g*16 + e)*32 + s]     = ((u32)(u16)cr[0][e]) | (((u32)(u16)cr[2][e]) << 16);
      wB[(g*16 + e)*32 + s]     = ((u32)(u16)cr[4][e]) | (((u32)(u16)cr[6][e]) << 16);
    }
    #pragma unroll
    for (int e=0;e<8;e++){
      const int s = (pc ^ e) * 4 + pl;
      wA[(g*16 + 8 + e)*32 + s] = ((u32)(u16)cr[1][e]) | (((u32)(u16)cr[3][e]) << 16);
      wB[(g*16 + 8 + e)*32 + s] = ((u32)(u16)cr[5][e]) | (((u32)(u16)cr[7][e]) << 16);
    }
    asm volatile("s_waitcnt lgkmcnt(0)" ::: "memory");
    FENCE_BARRIER();
    const int l15 = lane & 15;
    const int rx = l15 & 7;
    const int cq = lane >> 4;
    #pragma unroll
    for (int kk=0;kk<2;kk++){
      const int soff = (((kk*4 + cq) ^ rx) << 3);
      short8 af[4], bfv[4];
      #pragma unroll
      for (int mi=0;mi<4;mi++)
        af[mi] = *(const short8*)(lA + ((wr*64 + mi*16 + l15) << 6) + soff);
      #pragma unroll
      for (int ni=0;ni<4;ni++)
        bfv[ni] = *(const short8*)(lB + ((wc*64 + ni*16 + l15) << 6) + soff);
      #pragma unroll
      for (int mi=0;mi<4;mi++)
        #pragma unroll
        for (int ni=0;ni<4;ni++)
          acc[mi][ni] = __builtin_amdgcn_mfma_f32_16x16x32_bf16(af[mi], bfv[ni], acc[mi][ni], 0, 0, 0);
    }
    #pragma unroll
    for (int e=0;e<8;e++) cr[e] = nr[e];
  }

  float* dst = (z < 4) ? (part0 + ((size_t)z << 20)) : (part1 + ((size_t)(z-4) << 20));
  const int rbase = (lane >> 4) * 4;
  const int cidx = lane & 15;
  #pragma unroll
  for (int mi=0;mi<4;mi++)
    #pragma unroll
    for (int r=0;r<4;r++){
      const int i = i0 + wr*64 + mi*16 + rbase + r;
      #pragma unroll
      for (int ni=0;ni<4;ni++){
        const int j = j0 + wc*64 + ni*16 + cidx;
        dst[((size_t)i << 10) + j] = acc[mi][ni][r];
      }
    }
}

// ---------------------------------------------------------------- W_new (8 partial slices)
__global__ __launch_bounds__(256) void wnew_k(const float* __restrict__ part0,
                                              const float* __restrict__ part1,
                                              const float* __restrict__ memW,
                                              const float* __restrict__ fg,
                                              const float* __restrict__ lr,
                                              u16* __restrict__ out)
{
  int i = blockIdx.x*256 + threadIdx.x;
  float s = part0[i] + part0[i + (1<<20)] + part0[i + (2<<20)] + part0[i + (3<<20)]
          + part1[i] + part1[i + (1<<20)] + part1[i + (2<<20)] + part1[i + (3<<20)];
  const float scale = 2.f / ((float)NKV * 1024.f);
  float v = (1.f - fg[0])*memW[i] + lr[0]*scale*s;
  out[i] = f2bf(v);
}

// ---------------------------------------------------------------- x2 = LN(x1 + gate*x1 + (1-gate)*mo)
__global__ __launch_bounds__(256) void ln_gate(
    const u16* __restrict__ x1b, const u16* __restrict__ gateb,
    const u16* __restrict__ mob, const float* __restrict__ g2,
    const float* __restrict__ be2, u16* __restrict__ x2b)
{
  const int n = blockIdx.x;
  const int t = threadIdx.x, lane = t & 63, w = t >> 6;
  const size_t rb = (size_t)n << 8;
  ushort4 xa = ((const ushort4*)x1b)[rb+t];
  ushort4 ga = ((const ushort4*)gateb)[rb+t];
  ushort4 ma = ((const ushort4*)mob)[rb+t];
  float a0=bf2f(xa.x),a1=bf2f(xa.y),a2=bf2f(xa.z),a3=bf2f(xa.w);
  float g0=bf2f(ga.x),g1v=bf2f(ga.y),g2v=bf2f(ga.z),g3v=bf2f(ga.w);
  float m0=bf2f(ma.x),m1=bf2f(ma.y),m2=bf2f(ma.z),m3=bf2f(ma.w);
  float y0 = a0 + g0*a0 + (1.f-g0)*m0;
  float y1 = a1 + g1v*a1 + (1.f-g1v)*m1;
  float y2 = a2 + g2v*a2 + (1.f-g2v)*m2;
  float y3 = a3 + g3v*a3 + (1.f-g3v)*m3;
  float s1 = y0+y1+y2+y3;
  float s2 = y0*y0+y1*y1+y2*y2+y3*y3;
  #pragma unroll
  for (int off=32; off; off>>=1){ s1 += __shfl_xor(s1, off, 64); s2 += __shfl_xor(s2, off, 64); }
  __shared__ float rsh[8];
  if (lane == 0){ rsh[w] = s1; rsh[4+w] = s2; }
  __syncthreads();
  float S1 = rsh[0]+rsh[1]+rsh[2]+rsh[3];
  float S2 = rsh[4]+rsh[5]+rsh[6]+rsh[7];
  float mean = S1 * (1.f/1024.f);
  float var  = S2 * (1.f/1024.f) - mean*mean;
  float rstd = 1.f/sqrtf(var + 1e-5f);
  float4 gv = ((const float4*)g2)[t];
  float4 bv = ((const float4*)be2)[t];
  ushort4 ob;
  ob.x = f2bf((y0-mean)*rstd*gv.x + bv.x);
  ob.y = f2bf((y1-mean)*rstd*gv.y + bv.y);
  ob.z = f2bf((y2-mean)*rstd*gv.z + bv.z);
  ob.w = f2bf((y3-mean)*rstd*gv.w + bv.w);
  ((ushort4*)x2b)[rb + t] = ob;
}

// ---------------------------------------------------------------- out = LN(x2 + ff2) (ff2 in d_out, in-place)
__global__ __launch_bounds__(256) void ln_final(
    const u16* __restrict__ x2b, const float* __restrict__ g3,
    const float* __restrict__ be3, float* __restrict__ out)
{
  const int n = blockIdx.x;
  const int t = threadIdx.x, lane = t & 63, w = t >> 6;
  const size_t rb = (size_t)n << 8;
  ushort4 xa = ((const ushort4*)x2b)[rb+t];
  float4 f = ((const float4*)out)[rb+t];
  float y0 = bf2f(xa.x)+f.x, y1 = bf2f(xa.y)+f.y, y2 = bf2f(xa.z)+f.z, y3 = bf2f(xa.w)+f.w;
  float s1 = y0+y1+y2+y3;
  float s2 = y0*y0+y1*y1+y2*y2+y3*y3;
  #pragma unroll
  for (int off=32; off; off>>=1){ s1 += __shfl_xor(s1, off, 64); s2 += __shfl_xor(s2, off, 64); }
  __shared__ float rsh[8];
  if (lane == 0){ rsh[w] = s1; rsh[4+w] = s2; }
  __syncthreads();
  float S1 = rsh[0]+rsh[1]+rsh[2]+rsh[3];
  float S2 = rsh[4]+rsh[5]+rsh[6]+rsh[7];
  float mean = S1 * (1.f/1024.f);
  float var  = S2 * (1.f/1024.f) - mean*mean;
  float rstd = 1.f/sqrtf(var + 1e-5f);
  float4 gv = ((const float4*)g3)[t];
  float4 bv = ((const float4*)be3)[t];
  float4 o;
  o.x = (y0-mean)*rstd*gv.x + bv.x;
  o.y = (y1-mean)*rstd*gv.y + bv.y;
  o.z = (y2-mean)*rstd*gv.z + bv.z;
  o.w = (y3-mean)*rstd*gv.w + bv.w;
  ((float4*)out)[rb + t] = o;
}

// ================================================================ host
extern "C" void kernel_launch(void* const* d_in, const int* in_sizes, int n_in,
                              void* d_out, int out_size, void* d_ws, size_t ws_size,
                              hipStream_t stream)
{
  const float* x    = (const float*)d_in[0];
  const float* memW = (const float*)d_in[1];
  const float* memb = (const float*)d_in[2];
  const float* P    = (const float*)d_in[3];
  const float* Wi   = (const float*)d_in[4];
  const float* bi   = (const float*)d_in[5];
  const float* Wl1  = (const float*)d_in[6];
  const float* bl1  = (const float*)d_in[7];
  const float* Wl2  = (const float*)d_in[8];
  const float* bl2  = (const float*)d_in[9];
  const float* Wo   = (const float*)d_in[10];
  const float* bo   = (const float*)d_in[11];
  const float* fg   = (const float*)d_in[12];
  const float* lr   = (const float*)d_in[13];
  const float* Wg   = (const float*)d_in[14];
  const float* bg   = (const float*)d_in[15];
  const float* W1   = (const float*)d_in[16];
  const float* b1   = (const float*)d_in[17];
  const float* W2   = (const float*)d_in[18];
  const float* b2   = (const float*)d_in[19];
  const float* g1   = (const float*)d_in[20];
  const float* be1  = (const float*)d_in[21];
  const float* g2   = (const float*)d_in[22];
  const float* be2  = (const float*)d_in[23];
  const float* g3   = (const float*)d_in[24];
  const float* be3  = (const float*)d_in[25];
  float* out = (float*)d_out;

  const size_t SZ_TOK = (size_t)NTOK*1024*2;
  const size_t SZ_KV  = (size_t)NKV*1024*2;
  char* base = (char*)d_ws;
  size_t off = 0;
  auto alloc = [&](size_t bytes) -> char* {
    char* p = base + off;
    off += (bytes + 255) & ~(size_t)255;
    return p;
  };
  u16* x1b   = (u16*)alloc(SZ_TOK);
  u16* knb   = (u16*)alloc(SZ_KV);
  u16* h1b   = (u16*)alloc(SZ_KV);
  u16* hddb  = (u16*)alloc(SZ_KV);
  u16* kpb   = (u16*)alloc(SZ_KV);
  u16* wnewb = (u16*)alloc((size_t)1024*1024*2);
  u16* WiB   = (u16*)alloc((size_t)1024*1024*2);
  u16* Wl1B  = (u16*)alloc((size_t)1024*1024*2);
  u16* Wl2B  = (u16*)alloc((size_t)1024*1024*2);
  u16* memWB = (u16*)alloc((size_t)1024*1024*2);
  u16* WoB   = (u16*)alloc((size_t)1024*1024*2);
  u16* WgB   = (u16*)alloc((size_t)1024*2048*2);
  u16* W1B   = (u16*)alloc((size_t)4096*1024*2);
  u16* W2B   = (u16*)alloc((size_t)1024*4096*2);
  if (ws_size < off) return;   // diagnostic guard

  // aliases (lifetimes strictly sequential):
  u16*   diffb   = knb;            // knb dead after kp GEMM
  float* part0   = (float*)kpb;    // kpb dead after diff GEMM; grad slices 0-3
  float* part1   = (float*)h1b;    // h1b dead after hdd GEMM; grad slices 4-7 (consumed by wnew before mo writes mob)
  u16*   memoutb = knb;            // diffb dead after grad GEMM
  u16*   mob     = h1b;            // part1 dead after wnew_k
  u16*   gateb   = hddb;           // hddb dead after mo GEMM
  u16*   x2b     = kpb;            // part0 dead after wnew_k
  u16*   ff1b    = x1b;            // spans x1b+knb+h1b+hddb (67.2 MiB >= 64 MiB)

  cvt_all<<<2048, 256, 0, stream>>>(
      (const float4*)Wi, (const float4*)Wl1, (const float4*)Wl2, (const float4*)memW,
      (const float4*)Wo, (const float4*)Wg, (const float4*)W1, (const float4*)W2,
      (ushort4*)WiB, (ushort4*)Wl1B, (ushort4*)Wl2B, (ushort4*)memWB,
      (ushort4*)WoB, (ushort4*)WgB, (ushort4*)W1B, (ushort4*)W2B);

  attn_kv<<<NATTB + NKVB, 256, 0, stream>>>(x, P, g1, be1, x1b, knb);

  dim3 gkv(65, 8, 1);
  gemm_nt<2,0><<<gkv, 256, 0, stream>>>(knb, nullptr, WiB, bi, nullptr, nullptr, kpb, NKV, 1024, 1024, 1024, 1024);
  gemm_nt<1,0><<<gkv, 256, 0, stream>>>(kpb, nullptr, Wl1B, bl1, nullptr, nullptr, h1b, NKV, 1024, 1024, 1024, 1024);
  gemm_nt<1,0><<<gkv, 256, 0, stream>>>(h1b, nullptr, Wl2B, bl2, nullptr, nullptr, hddb, NKV, 1024, 1024, 1024, 1024);
  gemm_nt<4,0><<<gkv, 256, 0, stream>>>(hddb, nullptr, memWB, memb, kpb, nullptr, diffb, NKV, 1024, 1024, 1024, 1024);
  gemm_tn<<<dim3(8, 8, NSPLIT), 256, 0, stream>>>(diffb, hddb, part0, part1);
  wnew_k<<<4096, 256, 0, stream>>>(part0, part1, memW, fg, lr, wnewb);
  gemm_nt<2,0><<<gkv, 256, 0, stream>>>(hddb, nullptr, wnewb, memb, nullptr, nullptr, memoutb, NKV, 1024, 1024, 1024, 1024);
  gemm_nt<6,0><<<gkv, 256, 0, stream>>>(memoutb, nullptr, WoB, bo, nullptr, nullptr, mob, NKV, 1024, 1024, 1024, 1024);
  gemm_nt<5,1><<<dim3(64, 8, 1), 256, 0, stream>>>(x1b, mob, WgB, bg, nullptr, nullptr, gateb, NTOK, 1024, 1024, 2048, 2048);
  ln_gate<<<NTOK, 256, 0, stream>>>(x1b, gateb, mob, g2, be2, x2b);
  // ff1 = silu(x2 @ W1.T + b1) : 256x256 r6 4-slot kernel (512 blocks)
  gemm_256<1><<<dim3(32, 16, 1), 512, 0, stream>>>(x2b, W1B, b1, nullptr, ff1b, NTOK, 4096, 1024, 1024, 1024);
  // ff2 = ff1 @ W2.T + b2 -> f32 directly into d_out (128^2, 512 blocks, full chip)
  gemm_nt<0,0><<<dim3(64, 8, 1), 256, 0, stream>>>(ff1b, nullptr, W2B, b2, nullptr, out, nullptr, NTOK, 1024, 4096, 4096, 4096);
  ln_final<<<NTOK, 256, 0, stream>>>(x2b, g3, be3, out);
}